// Round 1
// baseline (830.305 us; speedup 1.0000x reference)
//
#include <hip/hip_runtime.h>
#include <math.h>

#define NBLK 512

// ---------------- wave helpers ----------------
__device__ __forceinline__ float wsum(float x) {
#pragma unroll
    for (int o = 1; o < 64; o <<= 1) x += __shfl_xor(x, o);
    return x;
}
__device__ __forceinline__ float wmaxr(float x) {
#pragma unroll
    for (int o = 1; o < 64; o <<= 1) x = fmaxf(x, __shfl_xor(x, o));
    return x;
}

// ---------------- device-wide generation barrier ----------------
// bar[0] = monotonic arrival counter, bar[1] = release generation.
// Zeroed by hipMemsetAsync before launch. Correct because all NBLK blocks are
// co-resident (64KiB LDS -> 2 blocks/CU, launch_bounds(256,2) -> VGPR<=256).
__device__ __forceinline__ void gsync(unsigned int* bar, unsigned int gen) {
    __syncthreads();
    if (threadIdx.x == 0) {
        __threadfence();                                   // release: wbL2+inv (agent scope)
        unsigned int arrived = atomicAdd(&bar[0], 1u) + 1u;
        if (arrived == gen * (unsigned int)NBLK) {
            atomicMax(&bar[1], gen);
        } else {
            while (atomicAdd(&bar[1], 0u) < gen) __builtin_amdgcn_s_sleep(2);
        }
        __threadfence();                                   // acquire
    }
    __syncthreads();
}

__global__ __launch_bounds__(256, 2) void k_mega(
    const float* __restrict__ nf, const float* __restrict__ ef,
    const int* __restrict__ nm, const int* __restrict__ em,
    const float* __restrict__ npw, const float* __restrict__ npb,
    const float* __restrict__ epw, const float* __restrict__ epb,
    const float* __restrict__ wq, const float* __restrict__ wk, const float* __restrict__ wvw,
    const float* __restrict__ eb1w, const float* __restrict__ eb1b,
    const float* __restrict__ eblng, const float* __restrict__ eblnb,
    const float* __restrict__ eb2w, const float* __restrict__ eb2b,
    const float* __restrict__ s1w, const float* __restrict__ s1b,
    const float* __restrict__ s2w, const float* __restrict__ s2b,
    const float* __restrict__ wow, const float* __restrict__ wob,
    const float* __restrict__ ln1g, const float* __restrict__ ln1b,
    const float* __restrict__ ln2g, const float* __restrict__ ln2b,
    const float* __restrict__ f1w, const float* __restrict__ f1b,
    const float* __restrict__ f2w, const float* __restrict__ f2b,
    const float* __restrict__ sc1w, const float* __restrict__ sc1b,
    const float* __restrict__ sclng, const float* __restrict__ sclnb,
    const float* __restrict__ sc2w, const float* __restrict__ sc2b,
    unsigned int* __restrict__ bar, unsigned long long* __restrict__ adj,
    unsigned char* __restrict__ spd, unsigned int* __restrict__ elist,
    unsigned int* __restrict__ rowCnt, float* __restrict__ vals,
    float* __restrict__ hbuf, float* __restrict__ Qb, float* __restrict__ KTb,
    float* __restrict__ VTb, float* __restrict__ attO, float* __restrict__ logits,
    float* __restrict__ out)
{
    const int t = threadIdx.x;
    const int wv = t >> 6;
    const int lane = t & 63;
    const int blk = blockIdx.x;
    __shared__ unsigned long long SMU[8192];      // 64 KiB, reused per phase
    float* SMf = (float*)SMU;
    unsigned int gen = 0u;

    // ---- qkv phase body (task tq in [0,128), 16 rows per block) ----
    auto qkv_phase = [&](int l, int tq) {
        float* h_lds = SMf;                       // [16][64]
        size_t base = (size_t)tq * 1024;
        for (int u = t; u < 1024; u += 256) h_lds[u] = hbuf[base + u];
        __syncthreads();
        const float* WQ = wq + l * 4096;
        const float* WK = wk + l * 4096;
        const float* WV = wvw + l * 4096;
        float aq[4] = {0,0,0,0}, ak[4] = {0,0,0,0}, av[4] = {0,0,0,0};
        for (int k = 0; k < 64; ++k) {
            float wqv = WQ[k*64+lane], wkv = WK[k*64+lane], wvv = WV[k*64+lane];
#pragma unroll
            for (int r = 0; r < 4; ++r) {
                float hv = h_lds[(wv*4+r)*64 + k];
                aq[r] += hv*wqv; ak[r] += hv*wkv; av[r] += hv*wvv;
            }
        }
#pragma unroll
        for (int r = 0; r < 4; ++r) Qb[base + (size_t)(wv*4+r)*64 + lane] = aq[r];
        int b = tq >> 5;
        int j0 = (tq & 31)*16 + wv*4;
        float4 kk; kk.x=ak[0]; kk.y=ak[1]; kk.z=ak[2]; kk.w=ak[3];
        float4 vv4; vv4.x=av[0]; vv4.y=av[1]; vv4.z=av[2]; vv4.w=av[3];
        *(float4*)(KTb + ((size_t)(b*64+lane))*512 + j0) = kk;
        *(float4*)(VTb + ((size_t)(b*64+lane))*512 + j0) = vv4;
    };

    // ---- edge-bias MLP for one row g (wave-level; ek shared across layers) ----
    auto edge_row = [&](int g) {
        unsigned int cnt = rowCnt[g];
        for (unsigned int s = lane; s < cnt; s += 64u) {
            unsigned int j = elist[g*96 + s];
            const float* e7 = ef + ((size_t)g*512 + j)*7;
            float f0=e7[0], f1=e7[1], f2=e7[2], f3=e7[3], f4=e7[4], f5=e7[5], f6=e7[6];
            float tt[3][16];
#pragma unroll
            for (int l = 0; l < 3; ++l)
#pragma unroll
                for (int c = 0; c < 16; ++c) tt[l][c] = eb1b[l*16+c];
            for (int k = 0; k < 64; ++k) {
                float ek = epb[k] + f0*epw[k] + f1*epw[64+k] + f2*epw[128+k]
                         + f3*epw[192+k] + f4*epw[256+k] + f5*epw[320+k] + f6*epw[384+k];
#pragma unroll
                for (int l = 0; l < 3; ++l) {
                    const float* W1 = eb1w + l*1024 + k*16;
#pragma unroll
                    for (int c = 0; c < 16; ++c) tt[l][c] += ek * W1[c];
                }
            }
#pragma unroll
            for (int l = 0; l < 3; ++l) {
                float m = 0.f;
#pragma unroll
                for (int c = 0; c < 16; ++c) m += tt[l][c];
                m *= 0.0625f;
                float var = 0.f;
#pragma unroll
                for (int c = 0; c < 16; ++c) { float d = tt[l][c] - m; var += d*d; }
                var *= 0.0625f;
                float inv = rsqrtf(var + 1e-5f);
#pragma unroll
                for (int c = 0; c < 16; ++c) {
                    float x = (tt[l][c]-m)*inv*eblng[l*16+c] + eblnb[l*16+c];
                    tt[l][c] = x >= 0.f ? x : 0.2f*x;
                }
#pragma unroll
                for (int hh = 0; hh < 4; ++hh) {
                    float a = eb2b[l*4+hh];
#pragma unroll
                    for (int c = 0; c < 16; ++c) a += tt[l][c]*eb2w[(l*16+c)*4+hh];
                    vals[(unsigned int)(l*4+hh)*196608u + (unsigned int)g*96u + s] = a;
                }
            }
        }
    };

    //========== P1: adjacency bitset + per-row edge compaction + node projection ==========
    {
        int g = blk*4 + wv;                        // row 0..2047
        const int* emr = em + (size_t)g * 512;
        unsigned int run = 0;
        for (int s = 0; s < 8; ++s) {
            int j = s*64 + lane;
            int v = emr[j];
            unsigned long long bal = __ballot(v != 0);
            if (v != 0) {
                unsigned int slot = run + (unsigned int)__popcll(bal & ((1ULL << lane) - 1ULL));
                if (slot < 96u) elist[g*96 + slot] = (unsigned int)j;
            }
            if (lane == 0) adj[g*8 + s] = bal;
            run += (unsigned int)__popcll(bal);
        }
        if (lane == 0) rowCnt[g] = run < 96u ? run : 96u;
        // node projection
        float acc = npb[lane];
        const float* r = nf + (size_t)g * 18;
#pragma unroll
        for (int c = 0; c < 18; ++c) acc += r[c] * npw[c*64 + lane];
        hbuf[(size_t)g*64 + lane] = acc;
    }
    gsync(bar, ++gen);

    //========== P2: BFS (all waves, 1 row each) ; then qkv(l=0) | edge-bias MLP ==========
    {
        unsigned long long* wb  = SMU + wv*96;     // per-wave region
        unsigned long long* vis = wb, *fro = wb + 8, *nxt = wb + 16, *dist8 = wb + 24;
        unsigned char* dist = (unsigned char*)dist8;
        int row = blk*4 + wv;
        int b = row >> 9, src = row & 511;
        dist8[lane] = 0x0A0A0A0A0A0A0A0AULL;
        if (lane < 8) { vis[lane] = 0ULL; fro[lane] = 0ULL; nxt[lane] = 0ULL; }
        __syncthreads();
        if (lane == 0) {
            dist[src] = 0;
            vis[src >> 6] = 1ULL << (src & 63);
            fro[src >> 6] = 1ULL << (src & 63);
        }
        __syncthreads();
        const unsigned long long* arow = adj + (size_t)b * 4096;
        for (int d = 1; d <= 9; ++d) {
            int c = lane >> 3, w = lane & 7;
            unsigned long long f = fro[c];
            unsigned long long acc = 0ULL;
            while (f) {
                int k = (c << 6) + __builtin_ctzll(f);
                f &= f - 1;
                acc |= arow[k*8 + w];
            }
            if (acc) atomicOr(&nxt[w], acc);
            __syncthreads();
            if (lane < 8) {
                unsigned long long nw = nxt[lane] & ~vis[lane];
                vis[lane] |= nw; fro[lane] = nw; nxt[lane] = 0ULL;
                while (nw) {
                    int j = (lane << 6) + __builtin_ctzll(nw);
                    nw &= nw - 1;
                    dist[j] = (unsigned char)d;
                }
            }
            __syncthreads();
        }
        ((unsigned long long*)(spd + (size_t)row * 512))[lane] = dist8[lane];
        __syncthreads();                            // SMU reuse below
        if (blk < 128) {
            qkv_phase(0, blk);
        } else {
            for (int g = (blk - 128)*4 + wv; g < 2048; g += 1536) edge_row(g);
        }
    }
    gsync(bar, ++gen);

    //========== layer loop ==========
    for (int l = 0; l < 3; ++l) {
        //---- attention: task = blk, bh = blk>>5 (tiles sharing bh are consecutive) ----
        {
            float* kt = SMf;                        // [16][512] K tile (reused as scratch)
            float* bv = SMf + 8192;                 // [16][512] bias tile, then V tile
            int bh = blk >> 5;
            int ty = blk & 31;
            int b = bh >> 2, hh = bh & 3;
            int i0 = ty * 16;
            int rbase = i0 + wv*4;
            float qv = Qb[((size_t)(b*512 + rbase + (lane>>4)))*64 + hh*16 + (lane&15)];
            float q[4][16];
#pragma unroll
            for (int r = 0; r < 4; ++r)
#pragma unroll
                for (int d = 0; d < 16; ++d) q[r][d] = __shfl(qv, r*16 + d);
            // stage K tile
            const float4* ktg = (const float4*)(KTb + (size_t)bh * 8192);
            float4* kts = (float4*)kt;
#pragma unroll
            for (int u = 0; u < 8; ++u) kts[t + u*256] = ktg[t + u*256];
            // spd bias table held in lane registers (lane L holds tab[L], L<11)
            float tval;
            {
                int li = lane < 11 ? lane : 10;
                float x = (float)li * 0.1f;
                float acc = s2b[l*4 + hh];
#pragma unroll
                for (int c = 0; c < 16; ++c) {
                    float v = x*s1w[l*16+c] + s1b[l*16+c];
                    v = v >= 0.f ? v : 0.2f*v;
                    acc += v*s2w[(l*16+c)*4 + hh];
                }
                tval = acc;
            }
            // bias tile init from spd bytes (values are 0..10 -> shfl lookup)
            const unsigned char* sp = spd + ((size_t)(b*512 + i0)) * 512;
#pragma unroll
            for (int u = 0; u < 8; ++u) {
                int e4 = u*1024 + t*4;
                unsigned int w4 = *(const unsigned int*)(sp + e4);
                bv[e4+0] = __shfl(tval, (int)(w4 & 255u));
                bv[e4+1] = __shfl(tval, (int)((w4 >> 8) & 255u));
                bv[e4+2] = __shfl(tval, (int)((w4 >> 16) & 255u));
                bv[e4+3] = __shfl(tval, (int)(w4 >> 24));
            }
            __syncthreads();                        // kt staged + bias init complete
            // sparse edge overlay (wave writes only its own 4 rows)
            unsigned int vp = (unsigned int)(l*4 + hh) * 196608u;
#pragma unroll
            for (int rr = 0; rr < 4; ++rr) {
                int g = b*512 + rbase + rr;
                unsigned int cnt = rowCnt[g];
                for (unsigned int s = lane; s < cnt; s += 64u) {
                    unsigned int j = elist[g*96 + s];
                    bv[(wv*4+rr)*512 + j] = vals[vp + (unsigned int)g*96u + s];
                }
            }
            // QK + bias + mask + softmax
            const int* nmb = nm + b*512;
            float sc[8][4];
            float mx[4] = {-3e38f, -3e38f, -3e38f, -3e38f};
#pragma unroll
            for (int c = 0; c < 8; ++c) {
                int j = c*64 + lane;
                float ktv[16];
#pragma unroll
                for (int d = 0; d < 16; ++d) ktv[d] = kt[d*512 + j];
                float madd = (nmb[j] != 0) ? 0.f : -1e9f;
#pragma unroll
                for (int r = 0; r < 4; ++r) {
                    float s = 0.f;
#pragma unroll
                    for (int d = 0; d < 16; ++d) s += q[r][d]*ktv[d];
                    s = s*0.25f + bv[(wv*4+r)*512 + j] + madd;
                    sc[c][r] = s;
                    mx[r] = fmaxf(mx[r], s);
                }
            }
#pragma unroll
            for (int r = 0; r < 4; ++r) mx[r] = wmaxr(mx[r]);
            float sm[4] = {0.f, 0.f, 0.f, 0.f};
#pragma unroll
            for (int c = 0; c < 8; ++c)
#pragma unroll
                for (int r = 0; r < 4; ++r) { sc[c][r] = __expf(sc[c][r] - mx[r]); sm[r] += sc[c][r]; }
#pragma unroll
            for (int r = 0; r < 4; ++r) sm[r] = 1.0f / wsum(sm[r]);
#pragma unroll
            for (int c = 0; c < 8; ++c)
#pragma unroll
                for (int r = 0; r < 4; ++r) sc[c][r] *= sm[r];
            __syncthreads();                        // all done reading bv (bias)
            // stage V tile
            const float4* vtg = (const float4*)(VTb + (size_t)bh * 8192);
            float4* vts = (float4*)bv;
#pragma unroll
            for (int u = 0; u < 8; ++u) vts[t + u*256] = vtg[t + u*256];
            __syncthreads();
            // PV
            float acc[4][16];
#pragma unroll
            for (int r = 0; r < 4; ++r)
#pragma unroll
                for (int d = 0; d < 16; ++d) acc[r][d] = 0.f;
#pragma unroll
            for (int c = 0; c < 8; ++c) {
                int j = c*64 + lane;
#pragma unroll
                for (int d = 0; d < 16; ++d) {
                    float v = bv[d*512 + j];
#pragma unroll
                    for (int r = 0; r < 4; ++r) acc[r][d] += sc[c][r]*v;
                }
            }
#pragma unroll
            for (int r = 0; r < 4; ++r)
#pragma unroll
                for (int d = 0; d < 16; ++d) {
                    acc[r][d] += __shfl_xor(acc[r][d], 16);
                    acc[r][d] += __shfl_xor(acc[r][d], 32);
                }
            // wave-local scratch in kt region (kt no longer read)
            float* scr = kt + wv*1040;
            if (lane < 16) {
#pragma unroll
                for (int r = 0; r < 4; ++r)
#pragma unroll
                    for (int d = 0; d < 16; ++d) scr[lane*65 + r*16 + d] = acc[r][d];
            }
            float o = 0.f;
#pragma unroll
            for (int m = 0; m < 16; ++m) o += scr[m*65 + lane];
            attO[((size_t)(b*512 + rbase + (lane>>4)))*64 + hh*16 + (lane&15)] = o;
        }
        gsync(bar, ++gen);

        //---- oproj + LN1 + FFN + LN2 (task = blk<128, 16 rows) ----
        if (blk < 128) {
            float* aO = SMf;                        // [16][64]
            float* hl = SMf + 1024;                 // [16][64]
            float* ff = SMf + 2048;                 // [16][256]
            size_t base = (size_t)blk * 1024;
            for (int u = t; u < 1024; u += 256) { aO[u] = attO[base + u]; hl[u] = hbuf[base + u]; }
            __syncthreads();
            const float* W = wow + l*4096;
            float x[4];
            {
                float wb0 = wob[l*64 + lane];
                float a0 = wb0, a1 = wb0, a2 = wb0, a3 = wb0;
                for (int k = 0; k < 64; ++k) {
                    float w = W[k*64 + lane];
                    a0 += aO[(wv*4+0)*64 + k]*w;
                    a1 += aO[(wv*4+1)*64 + k]*w;
                    a2 += aO[(wv*4+2)*64 + k]*w;
                    a3 += aO[(wv*4+3)*64 + k]*w;
                }
                x[0] = a0; x[1] = a1; x[2] = a2; x[3] = a3;
            }
            float g1 = ln1g[l*64 + lane], b1 = ln1b[l*64 + lane];
#pragma unroll
            for (int r = 0; r < 4; ++r) {
                float xx = x[r] + hl[(wv*4+r)*64 + lane];
                float mn = wsum(xx) * 0.015625f;
                float d = xx - mn;
                float var = wsum(d*d) * 0.015625f;
                hl[(wv*4+r)*64 + lane] = d*rsqrtf(var + 1e-5f)*g1 + b1;
            }
            // FFN (rows are wave-local in hl/ff)
            const float* W1 = f1w + l*16384;
            const float* B1 = f1b + l*256;
            const float* W2 = f2w + l*16384;
            float acc[4][4];
#pragma unroll
            for (int m = 0; m < 4; ++m) {
                float bvv = B1[m*64 + lane];
#pragma unroll
                for (int r = 0; r < 4; ++r) acc[m][r] = bvv;
            }
            for (int k = 0; k < 64; ++k) {
                float w0 = W1[k*256 + lane], w1 = W1[k*256 + 64 + lane],
                      w2 = W1[k*256 + 128 + lane], w3 = W1[k*256 + 192 + lane];
#pragma unroll
                for (int r = 0; r < 4; ++r) {
                    float hv = hl[(wv*4+r)*64 + k];
                    acc[0][r] += hv*w0; acc[1][r] += hv*w1;
                    acc[2][r] += hv*w2; acc[3][r] += hv*w3;
                }
            }
#pragma unroll
            for (int m = 0; m < 4; ++m)
#pragma unroll
                for (int r = 0; r < 4; ++r) {
                    float u = acc[m][r];
                    ff[(wv*4+r)*256 + m*64 + lane] = 0.5f*u*(1.0f + erff(u*0.70710678118654752f));
                }
            float a2[4] = {0.f, 0.f, 0.f, 0.f};
            for (int k = 0; k < 256; ++k) {
                float w = W2[k*64 + lane];
#pragma unroll
                for (int r = 0; r < 4; ++r) a2[r] += ff[(wv*4+r)*256 + k]*w;
            }
            float b2v = f2b[l*64 + lane], gv = ln2g[l*64 + lane], btv = ln2b[l*64 + lane];
#pragma unroll
            for (int r = 0; r < 4; ++r) {
                float xx = a2[r] + b2v + hl[(wv*4+r)*64 + lane];
                float mn = wsum(xx) * 0.015625f;
                float d = xx - mn;
                float var = wsum(d*d) * 0.015625f;
                float res = d*rsqrtf(var + 1e-5f)*gv + btv;
                hbuf[base + (size_t)(wv*4+r)*64 + lane] = res;
                if (l == 2) out[2044 + base + (wv*4+r)*64 + lane] = res;
            }
        }
        gsync(bar, ++gen);

        if (l < 2) {
            if (blk < 128) qkv_phase(l + 1, blk);
            gsync(bar, ++gen);
        }
    }

    //========== scoring head (wave per candidate) ==========
    if (blk < 511) {
        float* c = SMf + wv*128;
        int wid = blk*4 + wv;                       // 0..2043
        int b = wid / 511; int jj = wid % 511; int j = jj + 1;
        c[lane]      = hbuf[((size_t)b*512)*64 + lane];
        c[64 + lane] = hbuf[((size_t)(b*512 + j))*64 + lane];
        float acc = sc1b[lane];
#pragma unroll 8
        for (int k = 0; k < 128; ++k) acc += c[k]*sc1w[k*64 + lane];
        float mn = wsum(acc) * 0.015625f;
        float d = acc - mn;
        float var = wsum(d*d) * 0.015625f;
        float x = d*rsqrtf(var + 1e-5f)*sclng[lane] + sclnb[lane];
        x = x >= 0.f ? x : 0.2f*x;
        float p = wsum(x*sc2w[lane]);
        if (lane == 0) logits[wid] = p + sc2b[0];
    }
    gsync(bar, ++gen);

    //========== final softmax over candidates (blocks 0..3) ==========
    if (blk < 4) {
        float* red = SMf;                           // 256 floats
        int* anyp = (int*)(SMf + 512);
        int b = blk;
        bool c0 = (nm[b*512 + 1 + t] != 0);         // idx t in 0..255
        int i1 = t + 256;
        bool c1 = (i1 < 511) ? (nm[b*512 + 1 + i1] != 0) : false;
        if (t == 0) *anyp = 0;
        __syncthreads();
        if (c0 || c1) atomicOr(anyp, 1);
        __syncthreads();
        if (t == 0 && *anyp == 0) c0 = true;
        float v0 = c0 ? logits[b*511 + t] : -1e9f;
        float v1 = (i1 < 511 && c1) ? logits[b*511 + i1] : -1e9f;
        red[t] = fmaxf(v0, v1);
        __syncthreads();
        for (int s = 128; s > 0; s >>= 1) { if (t < s) red[t] = fmaxf(red[t], red[t + s]); __syncthreads(); }
        float m = red[0];
        __syncthreads();
        float p0 = __expf(v0 - m);
        float p1 = (i1 < 511) ? __expf(v1 - m) : 0.f;
        red[t] = p0 + p1;
        __syncthreads();
        for (int s = 128; s > 0; s >>= 1) { if (t < s) red[t] += red[t + s]; __syncthreads(); }
        float inv = 1.0f / red[0];
        out[b*511 + t] = p0*inv;
        if (i1 < 511) out[b*511 + i1] = p1*inv;
    }
}

extern "C" void kernel_launch(void* const* d_in, const int* in_sizes, int n_in,
                              void* d_out, int out_size, void* d_ws, size_t ws_size,
                              hipStream_t stream) {
    const float* nf    = (const float*)d_in[0];
    const float* ef    = (const float*)d_in[1];
    const int*   nm    = (const int*)d_in[2];
    const int*   em    = (const int*)d_in[3];
    const float* npw   = (const float*)d_in[4];
    const float* npb   = (const float*)d_in[5];
    const float* epw   = (const float*)d_in[6];
    const float* epb   = (const float*)d_in[7];
    const float* wq    = (const float*)d_in[8];
    const float* wk    = (const float*)d_in[9];
    const float* wv    = (const float*)d_in[10];
    const float* eb1w  = (const float*)d_in[11];
    const float* eb1b  = (const float*)d_in[12];
    const float* eblng = (const float*)d_in[13];
    const float* eblnb = (const float*)d_in[14];
    const float* eb2w  = (const float*)d_in[15];
    const float* eb2b  = (const float*)d_in[16];
    const float* s1wv  = (const float*)d_in[17];
    const float* s1bv  = (const float*)d_in[18];
    const float* s2wv  = (const float*)d_in[19];
    const float* s2bv  = (const float*)d_in[20];
    const float* wow   = (const float*)d_in[21];
    const float* wob   = (const float*)d_in[22];
    const float* ln1g  = (const float*)d_in[23];
    const float* ln1b  = (const float*)d_in[24];
    const float* ln2g  = (const float*)d_in[25];
    const float* ln2b  = (const float*)d_in[26];
    const float* f1w   = (const float*)d_in[27];
    const float* f1b   = (const float*)d_in[28];
    const float* f2w   = (const float*)d_in[29];
    const float* f2b   = (const float*)d_in[30];
    const float* sc1w  = (const float*)d_in[31];
    const float* sc1b  = (const float*)d_in[32];
    const float* sclng = (const float*)d_in[33];
    const float* sclnb = (const float*)d_in[34];
    const float* sc2w  = (const float*)d_in[35];
    const float* sc2b  = (const float*)d_in[36];

    char* W = (char*)d_ws;
    unsigned int*       bar    = (unsigned int*)(W + 0);              // 64 B (zeroed)
    unsigned long long* adj    = (unsigned long long*)(W + 1024);     // 131,072 B
    unsigned char*      spd    = (unsigned char*)(W + 132096);        // 1,048,576 B
    unsigned int*       elist  = (unsigned int*)(W + 1180672);        // 786,432 B  [2048][96]
    unsigned int*       rowCnt = (unsigned int*)(W + 1967104);        // 8,192 B
    float*              vals   = (float*)(W + 1975296);               // 9,437,184 B [12][2048*96]
    float*              hbuf   = (float*)(W + 11412480);              // 524,288 B
    float*              Qb     = (float*)(W + 11936768);              // 524,288 B
    float*              KTb    = (float*)(W + 12461056);              // 524,288 B
    float*              VTb    = (float*)(W + 12985344);              // 524,288 B
    float*              attO   = (float*)(W + 13509632);              // 524,288 B
    float*              logits = (float*)(W + 14033920);              // 8,192 B

    float* out = (float*)d_out;                  // [probs 2044][h 131072]

    hipMemsetAsync(bar, 0, 16, stream);
    hipLaunchKernelGGL(k_mega, dim3(NBLK), dim3(256), 0, stream,
        nf, ef, nm, em, npw, npb, epw, epb, wq, wk, wv,
        eb1w, eb1b, eblng, eblnb, eb2w, eb2b,
        s1wv, s1bv, s2wv, s2bv, wow, wob,
        ln1g, ln1b, ln2g, ln2b, f1w, f1b, f2w, f2b,
        sc1w, sc1b, sclng, sclnb, sc2w, sc2b,
        bar, adj, spd, elist, rowCnt, vals,
        hbuf, Qb, KTb, VTb, attO, logits, out);
}

// Round 2
// 608.922 us; speedup vs baseline: 1.3636x; 1.3636x over previous
//
#include <hip/hip_runtime.h>
#include <math.h>

#define NBLK 256

typedef unsigned long long u64;
typedef unsigned int u32;

// ---------------- wave helpers ----------------
__device__ __forceinline__ float wsum(float x) {
#pragma unroll
    for (int o = 1; o < 64; o <<= 1) x += __shfl_xor(x, o);
    return x;
}
__device__ __forceinline__ float wmaxr(float x) {
#pragma unroll
    for (int o = 1; o < 64; o <<= 1) x = fmaxf(x, __shfl_xor(x, o));
    return x;
}

// ---------------- coherent (cross-XCD) scalar ops: relaxed agent atomics ----------------
// These compile to global_load/store with sc bits -> coherence point (bypass the
// non-coherent per-XCD L2). No cache-flush fences anywhere in this kernel.
__device__ __forceinline__ float cld(const float* p) {
    return __hip_atomic_load(p, __ATOMIC_RELAXED, __HIP_MEMORY_SCOPE_AGENT);
}
__device__ __forceinline__ void cst(float* p, float v) {
    __hip_atomic_store(p, v, __ATOMIC_RELAXED, __HIP_MEMORY_SCOPE_AGENT);
}
__device__ __forceinline__ void cst64(u64* p, u64 v) {
    __hip_atomic_store(p, v, __ATOMIC_RELAXED, __HIP_MEMORY_SCOPE_AGENT);
}

// ---------------- coherent bulk stage: 32KB global -> LDS, 8 dwordx4 in flight/thread ----
__device__ __forceinline__ void stage32k(float* dstLDS, const float* srcG, int t) {
    const float4* s = (const float4*)srcG;
    float4* d = (float4*)dstLDS;
    float4 r0, r1, r2, r3, r4, r5, r6, r7;
    asm volatile(
        "global_load_dwordx4 %0, %8, off sc0 sc1\n\t"
        "global_load_dwordx4 %1, %9, off sc0 sc1\n\t"
        "global_load_dwordx4 %2, %10, off sc0 sc1\n\t"
        "global_load_dwordx4 %3, %11, off sc0 sc1\n\t"
        "global_load_dwordx4 %4, %12, off sc0 sc1\n\t"
        "global_load_dwordx4 %5, %13, off sc0 sc1\n\t"
        "global_load_dwordx4 %6, %14, off sc0 sc1\n\t"
        "global_load_dwordx4 %7, %15, off sc0 sc1\n\t"
        "s_waitcnt vmcnt(0)"
        : "=&v"(r0), "=&v"(r1), "=&v"(r2), "=&v"(r3),
          "=&v"(r4), "=&v"(r5), "=&v"(r6), "=&v"(r7)
        : "v"(s + t), "v"(s + t + 256), "v"(s + t + 512), "v"(s + t + 768),
          "v"(s + t + 1024), "v"(s + t + 1280), "v"(s + t + 1536), "v"(s + t + 1792)
        : "memory");
    d[t] = r0; d[t + 256] = r1; d[t + 512] = r2; d[t + 768] = r3;
    d[t + 1024] = r4; d[t + 1280] = r5; d[t + 1536] = r6; d[t + 1792] = r7;
}

// ---------------- fence-free device barrier ----------------
// __syncthreads() drains each wave's vmcnt (compiler emits full waitcnt before s_barrier),
// so all coherent stores of the block are globally visible before arrival.
// Hierarchical arrival (16 groups of 16, 128B-spaced lines) + load-only spin.
__device__ __forceinline__ void gsync(u32* bar, u32 gen) {
    __syncthreads();
    if (threadIdx.x == 0) {
        asm volatile("s_waitcnt vmcnt(0)" ::: "memory");
        u32 g = blockIdx.x & 15u;
        u32 a = __hip_atomic_fetch_add(&bar[32 + g * 32], 1u,
                                       __ATOMIC_RELAXED, __HIP_MEMORY_SCOPE_AGENT) + 1u;
        if (a == gen * 16u) {
            u32 r = __hip_atomic_fetch_add(&bar[16], 1u,
                                           __ATOMIC_RELAXED, __HIP_MEMORY_SCOPE_AGENT) + 1u;
            if (r == gen * 16u)
                __hip_atomic_store(&bar[0], gen, __ATOMIC_RELAXED, __HIP_MEMORY_SCOPE_AGENT);
        }
        while (__hip_atomic_load(&bar[0], __ATOMIC_RELAXED, __HIP_MEMORY_SCOPE_AGENT) < gen)
            __builtin_amdgcn_s_sleep(2);
    }
    __syncthreads();
}

__global__ __launch_bounds__(256, 2) void k_mega(
    const float* __restrict__ nf, const float* __restrict__ ef,
    const int* __restrict__ nm, const int* __restrict__ em,
    const float* __restrict__ npw, const float* __restrict__ npb,
    const float* __restrict__ epw, const float* __restrict__ epb,
    const float* __restrict__ wq, const float* __restrict__ wk, const float* __restrict__ wvw,
    const float* __restrict__ eb1w, const float* __restrict__ eb1b,
    const float* __restrict__ eblng, const float* __restrict__ eblnb,
    const float* __restrict__ eb2w, const float* __restrict__ eb2b,
    const float* __restrict__ s1w, const float* __restrict__ s1b,
    const float* __restrict__ s2w, const float* __restrict__ s2b,
    const float* __restrict__ wow, const float* __restrict__ wob,
    const float* __restrict__ ln1g, const float* __restrict__ ln1b,
    const float* __restrict__ ln2g, const float* __restrict__ ln2b,
    const float* __restrict__ f1w, const float* __restrict__ f1b,
    const float* __restrict__ f2w, const float* __restrict__ f2b,
    const float* __restrict__ sc1w, const float* __restrict__ sc1b,
    const float* __restrict__ sclng, const float* __restrict__ sclnb,
    const float* __restrict__ sc2w, const float* __restrict__ sc2b,
    u32* __restrict__ bar, u64* __restrict__ adj, float* __restrict__ vals,
    float* __restrict__ KT0, float* __restrict__ VT0,
    float* __restrict__ KT1, float* __restrict__ VT1,
    float* __restrict__ hbuf, float* __restrict__ logits, float* __restrict__ out)
{
    const int t = threadIdx.x;
    const int wv = t >> 6;
    const int lane = t & 63;
    const int blk = blockIdx.x;
    const int b = blk >> 6;           // batch (64 blocks per batch)
    u32 gen = 0u;

    // Block owns 8 contiguous rows: global rows blk*8 .. blk*8+7  (i0 = (blk&63)*8 in batch)
    __shared__ float MAIN[12288];                 // 48 KiB phase scratch
    __shared__ float Hlds[512];                   // [8][64] persistent h
    __shared__ float Qlds[512];                   // [8][64] persistent Q (current layer)
    __shared__ float ATTO[512];                   // [8][64] attention output
    __shared__ unsigned char SPDl[4096];          // [8][512] spd bytes (own rows)
    __shared__ u32 ELISTl[768];                   // [8][96] edge col indices (own rows)
    __shared__ u32 EcntL[8];

    // ---- qkv for layer l: own 8 rows, Hlds -> Qlds + coherent K/V (parity buffer) ----
    auto qkv_do = [&](int l) {
        const float* WQ = wq + l * 4096;
        const float* WK = wk + l * 4096;
        const float* WV = wvw + l * 4096;
        float* KT = (l & 1) ? KT1 : KT0;
        float* VT = (l & 1) ? VT1 : VT0;
        float aq[2] = {0, 0}, ak[2] = {0, 0}, av[2] = {0, 0};
        for (int k = 0; k < 64; ++k) {
            float wqv = WQ[k * 64 + lane], wkv = WK[k * 64 + lane], wvv = WV[k * 64 + lane];
#pragma unroll
            for (int rr = 0; rr < 2; ++rr) {
                float hv = Hlds[(wv * 2 + rr) * 64 + k];
                aq[rr] += hv * wqv; ak[rr] += hv * wkv; av[rr] += hv * wvv;
            }
        }
        size_t basekv = ((size_t)(b * 64 + lane)) * 512 + (size_t)(blk & 63) * 8 + wv * 2;
#pragma unroll
        for (int rr = 0; rr < 2; ++rr) {
            Qlds[(wv * 2 + rr) * 64 + lane] = aq[rr];
            cst(KT + basekv + rr, ak[rr]);
            cst(VT + basekv + rr, av[rr]);
        }
    };

    //========== P1: adjacency bitsets + per-row edge list (LDS) + node projection ==========
    {
#pragma unroll 1
        for (int rr = 0; rr < 2; ++rr) {
            int rl = wv * 2 + rr;
            int g = blk * 8 + rl;
            const int* emr = em + (size_t)g * 512;
            u32 run = 0;
            for (int s = 0; s < 8; ++s) {
                int j = s * 64 + lane;
                int v = emr[j];
                u64 bal = __ballot(v != 0);
                if (v != 0) {
                    u32 slot = run + (u32)__popcll(bal & ((1ULL << lane) - 1ULL));
                    if (slot < 96u) ELISTl[rl * 96 + slot] = (u32)j;
                }
                if (lane == 0) cst64(adj + (size_t)g * 8 + s, bal);
                run += (u32)__popcll(bal);
            }
            if (lane == 0) EcntL[rl] = run < 96u ? run : 96u;
            // node projection -> Hlds
            float acc = npb[lane];
            const float* r = nf + (size_t)g * 18;
#pragma unroll
            for (int c = 0; c < 18; ++c) acc += r[c] * npw[c * 64 + lane];
            Hlds[rl * 64 + lane] = acc;
        }
    }
    gsync(bar, ++gen);

    //========== P2: BFS (adj batch in LDS) -> SPDl ; then qkv(0) ; then edge MLP ==========
    {
        stage32k(MAIN, (const float*)(adj + (size_t)b * 4096), t);
        __syncthreads();
        u64* adjL = (u64*)MAIN;                    // [512][8]
        u64* wb = adjL + 4096 + wv * 96;           // per-wave scratch
        u64* vis = wb; u64* fro = wb + 8; u64* nxt = wb + 16; u64* dist8 = wb + 24;
        unsigned char* dist = (unsigned char*)dist8;
#pragma unroll 1
        for (int rr = 0; rr < 2; ++rr) {
            int rl = wv * 2 + rr;
            int srow = (blk & 63) * 8 + rl;
            dist8[lane] = 0x0A0A0A0A0A0A0A0AULL;
            if (lane < 8) { vis[lane] = 0ULL; fro[lane] = 0ULL; nxt[lane] = 0ULL; }
            __syncthreads();
            if (lane == 0) {
                dist[srow] = 0;
                vis[srow >> 6] = 1ULL << (srow & 63);
                fro[srow >> 6] = 1ULL << (srow & 63);
            }
            __syncthreads();
            for (int d = 1; d <= 9; ++d) {
                int c = lane >> 3, w = lane & 7;
                u64 f = fro[c];
                u64 acc = 0ULL;
                while (f) {
                    int k = (c << 6) + __builtin_ctzll(f);
                    f &= f - 1;
                    acc |= adjL[k * 8 + w];
                }
                if (acc) atomicOr(&nxt[w], acc);
                __syncthreads();
                if (lane < 8) {
                    u64 nw = nxt[lane] & ~vis[lane];
                    vis[lane] |= nw; fro[lane] = nw; nxt[lane] = 0ULL;
                    while (nw) {
                        int j = (lane << 6) + __builtin_ctzll(nw);
                        nw &= nw - 1;
                        dist[j] = (unsigned char)d;
                    }
                }
                __syncthreads();
            }
            ((u64*)SPDl)[rl * 64 + lane] = dist8[lane];
            __syncthreads();
        }
        // qkv for layer 0 (Hlds ready since P1; own rows)
        qkv_do(0);
        // edge-bias MLP (own rows; edge projection shared across the 3 layers)
#pragma unroll 1
        for (int rr = 0; rr < 2; ++rr) {
            int rl = wv * 2 + rr;
            int g = blk * 8 + rl;
            u32 cnt = EcntL[rl];
            for (u32 s = lane; s < cnt; s += 64u) {
                u32 j = ELISTl[rl * 96 + s];
                const float* e7 = ef + ((size_t)g * 512 + j) * 7;
                float f0 = e7[0], f1 = e7[1], f2 = e7[2], f3 = e7[3], f4 = e7[4], f5 = e7[5], f6 = e7[6];
                float tt[3][16];
#pragma unroll
                for (int l = 0; l < 3; ++l)
#pragma unroll
                    for (int c = 0; c < 16; ++c) tt[l][c] = eb1b[l * 16 + c];
                for (int k = 0; k < 64; ++k) {
                    float ek = epb[k] + f0 * epw[k] + f1 * epw[64 + k] + f2 * epw[128 + k]
                             + f3 * epw[192 + k] + f4 * epw[256 + k] + f5 * epw[320 + k]
                             + f6 * epw[384 + k];
#pragma unroll
                    for (int l = 0; l < 3; ++l) {
                        const float* W1 = eb1w + l * 1024 + k * 16;
#pragma unroll
                        for (int c = 0; c < 16; ++c) tt[l][c] += ek * W1[c];
                    }
                }
#pragma unroll
                for (int l = 0; l < 3; ++l) {
                    float m = 0.f;
#pragma unroll
                    for (int c = 0; c < 16; ++c) m += tt[l][c];
                    m *= 0.0625f;
                    float var = 0.f;
#pragma unroll
                    for (int c = 0; c < 16; ++c) { float d = tt[l][c] - m; var += d * d; }
                    var *= 0.0625f;
                    float inv = rsqrtf(var + 1e-5f);
#pragma unroll
                    for (int c = 0; c < 16; ++c) {
                        float x = (tt[l][c] - m) * inv * eblng[l * 16 + c] + eblnb[l * 16 + c];
                        tt[l][c] = x >= 0.f ? x : 0.2f * x;
                    }
#pragma unroll
                    for (int hh = 0; hh < 4; ++hh) {
                        float a = eb2b[l * 4 + hh];
#pragma unroll
                        for (int c = 0; c < 16; ++c) a += tt[l][c] * eb2w[(l * 16 + c) * 4 + hh];
                        vals[(u32)(l * 4 + hh) * 196608u + (u32)g * 96u + s] = a;   // block-local
                    }
                }
            }
        }
    }
    gsync(bar, ++gen);

    //========== layer loop: attn (4 heads seq) + oproj/LN1 + FFN/LN2 + qkv(l+1) ==========
    for (int l = 0; l < 3; ++l) {
        const float* KT = (l & 1) ? KT1 : KT0;
        const float* VT = (l & 1) ? VT1 : VT0;
        float* ktl = MAIN;                 // [16][512] K (then V) tile
        float* bv8 = MAIN + 8192;          // [8][512] bias tile / PV scratch
#pragma unroll 1
        for (int hh = 0; hh < 4; ++hh) {
            stage32k(ktl, KT + ((size_t)(b * 64 + hh * 16)) * 512, t);
            // spd-bias table in lane registers (lane L holds tab[L], L<11)
            float tval;
            {
                int li = lane < 11 ? lane : 10;
                float x = (float)li * 0.1f;
                float a = s2b[l * 4 + hh];
#pragma unroll
                for (int c = 0; c < 16; ++c) {
                    float v = x * s1w[l * 16 + c] + s1b[l * 16 + c];
                    v = v >= 0.f ? v : 0.2f * v;
                    a += v * s2w[(l * 16 + c) * 4 + hh];
                }
                tval = a;
            }
            // bias tile from SPD bytes
#pragma unroll
            for (int p = 0; p < 4; ++p) {
                int i32 = t + p * 256;
                u32 w4 = ((const u32*)SPDl)[i32];
                bv8[i32 * 4 + 0] = __shfl(tval, (int)(w4 & 255u));
                bv8[i32 * 4 + 1] = __shfl(tval, (int)((w4 >> 8) & 255u));
                bv8[i32 * 4 + 2] = __shfl(tval, (int)((w4 >> 16) & 255u));
                bv8[i32 * 4 + 3] = __shfl(tval, (int)(w4 >> 24));
            }
            __syncthreads();
            // sparse edge overlay (own-wave rows)
            u32 vp = (u32)(l * 4 + hh) * 196608u;
#pragma unroll
            for (int rr = 0; rr < 2; ++rr) {
                int rl = wv * 2 + rr;
                int g = blk * 8 + rl;
                u32 cnt = EcntL[rl];
                for (u32 s = lane; s < cnt; s += 64u) {
                    u32 j = ELISTl[rl * 96 + s];
                    bv8[rl * 512 + j] = vals[vp + (u32)g * 96u + s];
                }
            }
            // Q fragments (LDS broadcast)
            float q[2][16];
#pragma unroll
            for (int rr = 0; rr < 2; ++rr)
#pragma unroll
                for (int d = 0; d < 16; ++d) q[rr][d] = Qlds[(wv * 2 + rr) * 64 + hh * 16 + d];
            // QK + bias + mask + softmax
            const int* nmb = nm + b * 512;
            float sc[8][2];
            float mx[2] = {-3e38f, -3e38f};
#pragma unroll
            for (int c = 0; c < 8; ++c) {
                int j = c * 64 + lane;
                float ktv[16];
#pragma unroll
                for (int d = 0; d < 16; ++d) ktv[d] = ktl[d * 512 + j];
                float madd = (nmb[j] != 0) ? 0.f : -1e9f;
#pragma unroll
                for (int rr = 0; rr < 2; ++rr) {
                    float s = 0.f;
#pragma unroll
                    for (int d = 0; d < 16; ++d) s += q[rr][d] * ktv[d];
                    s = s * 0.25f + bv8[(wv * 2 + rr) * 512 + j] + madd;
                    sc[c][rr] = s;
                    mx[rr] = fmaxf(mx[rr], s);
                }
            }
#pragma unroll
            for (int rr = 0; rr < 2; ++rr) mx[rr] = wmaxr(mx[rr]);
            float sm[2] = {0.f, 0.f};
#pragma unroll
            for (int c = 0; c < 8; ++c)
#pragma unroll
                for (int rr = 0; rr < 2; ++rr) { sc[c][rr] = __expf(sc[c][rr] - mx[rr]); sm[rr] += sc[c][rr]; }
#pragma unroll
            for (int rr = 0; rr < 2; ++rr) sm[rr] = 1.0f / wsum(sm[rr]);
#pragma unroll
            for (int c = 0; c < 8; ++c)
#pragma unroll
                for (int rr = 0; rr < 2; ++rr) sc[c][rr] *= sm[rr];
            __syncthreads();                 // done reading K tile + bias
            // stage V over K tile
            stage32k(ktl, VT + ((size_t)(b * 64 + hh * 16)) * 512, t);
            __syncthreads();
            // PV
            float acc[2][16];
#pragma unroll
            for (int rr = 0; rr < 2; ++rr)
#pragma unroll
                for (int d = 0; d < 16; ++d) acc[rr][d] = 0.f;
#pragma unroll
            for (int c = 0; c < 8; ++c) {
                int j = c * 64 + lane;
#pragma unroll
                for (int d = 0; d < 16; ++d) {
                    float v = ktl[d * 512 + j];
#pragma unroll
                    for (int rr = 0; rr < 2; ++rr) acc[rr][d] += sc[c][rr] * v;
                }
            }
#pragma unroll
            for (int rr = 0; rr < 2; ++rr)
#pragma unroll
                for (int d = 0; d < 16; ++d) {
                    acc[rr][d] += __shfl_xor(acc[rr][d], 16);
                    acc[rr][d] += __shfl_xor(acc[rr][d], 32);
                }
            float* scr = bv8 + wv * 544;     // 16 x stride-33, wave-private
            if (lane < 16) {
#pragma unroll
                for (int rr = 0; rr < 2; ++rr)
#pragma unroll
                    for (int d = 0; d < 16; ++d) scr[lane * 33 + rr * 16 + d] = acc[rr][d];
            }
            if (lane < 32) {
                float o = 0.f;
#pragma unroll
                for (int m = 0; m < 16; ++m) o += scr[m * 33 + lane];
                ATTO[(wv * 2 + (lane >> 4)) * 64 + hh * 16 + (lane & 15)] = o;
            }
            __syncthreads();                 // head done (ktl/bv8 reusable)
        }
        // ---- output projection + residual + LN1 (own rows) ----
        {
            const float* Wo = wow + l * 4096;
            float wb0 = wob[l * 64 + lane];
            float a0 = wb0, a1 = wb0;
            for (int k = 0; k < 64; ++k) {
                float w = Wo[k * 64 + lane];
                a0 += ATTO[(wv * 2 + 0) * 64 + k] * w;
                a1 += ATTO[(wv * 2 + 1) * 64 + k] * w;
            }
            float xo[2] = {a0, a1};
            float g1 = ln1g[l * 64 + lane], b1 = ln1b[l * 64 + lane];
#pragma unroll
            for (int rr = 0; rr < 2; ++rr) {
                float xx = xo[rr] + Hlds[(wv * 2 + rr) * 64 + lane];
                float mn = wsum(xx) * 0.015625f;
                float d = xx - mn;
                float var = wsum(d * d) * 0.015625f;
                Hlds[(wv * 2 + rr) * 64 + lane] = d * rsqrtf(var + 1e-5f) * g1 + b1;
            }
        }
        // ---- FFN + residual + LN2 (own rows; ff in MAIN) ----
        {
            float* ff = MAIN;                // [8][256]
            const float* W1 = f1w + l * 16384;
            const float* B1 = f1b + l * 256;
            const float* W2 = f2w + l * 16384;
            float a1v[4][2];
#pragma unroll
            for (int m = 0; m < 4; ++m) {
                float bb = B1[m * 64 + lane];
                a1v[m][0] = bb; a1v[m][1] = bb;
            }
            for (int k = 0; k < 64; ++k) {
                float w0 = W1[k * 256 + lane], w1 = W1[k * 256 + 64 + lane],
                      w2 = W1[k * 256 + 128 + lane], w3 = W1[k * 256 + 192 + lane];
#pragma unroll
                for (int rr = 0; rr < 2; ++rr) {
                    float hv = Hlds[(wv * 2 + rr) * 64 + k];
                    a1v[0][rr] += hv * w0; a1v[1][rr] += hv * w1;
                    a1v[2][rr] += hv * w2; a1v[3][rr] += hv * w3;
                }
            }
#pragma unroll
            for (int m = 0; m < 4; ++m)
#pragma unroll
                for (int rr = 0; rr < 2; ++rr) {
                    float u = a1v[m][rr];
                    ff[(wv * 2 + rr) * 256 + m * 64 + lane] = 0.5f * u * (1.0f + erff(u * 0.70710678118654752f));
                }
            float a2[2] = {0.f, 0.f};
            for (int k = 0; k < 256; ++k) {
                float w = W2[k * 64 + lane];
#pragma unroll
                for (int rr = 0; rr < 2; ++rr) a2[rr] += ff[(wv * 2 + rr) * 256 + k] * w;
            }
            float b2v = f2b[l * 64 + lane], gv = ln2g[l * 64 + lane], btv = ln2b[l * 64 + lane];
#pragma unroll
            for (int rr = 0; rr < 2; ++rr) {
                float xx = a2[rr] + b2v + Hlds[(wv * 2 + rr) * 64 + lane];
                float mn = wsum(xx) * 0.015625f;
                float d = xx - mn;
                float var = wsum(d * d) * 0.015625f;
                float res = d * rsqrtf(var + 1e-5f) * gv + btv;
                Hlds[(wv * 2 + rr) * 64 + lane] = res;
                if (l == 2) {
                    size_t gr = (size_t)(blk * 8 + wv * 2 + rr);
                    cst(hbuf + gr * 64 + lane, res);          // coherent: read by score
                    out[2044 + gr * 64 + lane] = res;          // plain: host-visible at kernel end
                }
            }
        }
        if (l < 2) qkv_do(l + 1);
        gsync(bar, ++gen);
    }

    //========== scoring head: 8 candidates per block (2 per wave, sequential) ==========
    {
        float* c = MAIN + wv * 128;
#pragma unroll 1
        for (int rr = 0; rr < 2; ++rr) {
            int wid = blk * 8 + wv * 2 + rr;
            if (wid < 2044) {
                int bb = wid / 511; int jj = wid % 511; int j = jj + 1;
                c[lane] = cld(hbuf + (size_t)bb * 32768 + lane);
                c[64 + lane] = cld(hbuf + ((size_t)(bb * 512 + j)) * 64 + lane);
                float acc = sc1b[lane];
#pragma unroll 8
                for (int k = 0; k < 128; ++k) acc += c[k] * sc1w[k * 64 + lane];
                float mn = wsum(acc) * 0.015625f;
                float d = acc - mn;
                float var = wsum(d * d) * 0.015625f;
                float x = d * rsqrtf(var + 1e-5f) * sclng[lane] + sclnb[lane];
                x = x >= 0.f ? x : 0.2f * x;
                float p = wsum(x * sc2w[lane]);
                if (lane == 0) cst(logits + wid, p + sc2b[0]);
            }
        }
    }
    gsync(bar, ++gen);

    //========== final softmax over candidates (blocks 0..3) ==========
    if (blk < 4) {
        float* red = MAIN;
        int* anyp = (int*)(MAIN + 512);
        int bb = blk;
        bool c0 = (nm[bb * 512 + 1 + t] != 0);
        int i1 = t + 256;
        bool c1 = (i1 < 511) ? (nm[bb * 512 + 1 + i1] != 0) : false;
        if (t == 0) *anyp = 0;
        __syncthreads();
        if (c0 || c1) atomicOr(anyp, 1);
        __syncthreads();
        if (t == 0 && *anyp == 0) c0 = true;
        float v0 = c0 ? cld(logits + bb * 511 + t) : -1e9f;
        float v1 = (i1 < 511 && c1) ? cld(logits + bb * 511 + i1) : -1e9f;
        red[t] = fmaxf(v0, v1);
        __syncthreads();
        for (int s = 128; s > 0; s >>= 1) { if (t < s) red[t] = fmaxf(red[t], red[t + s]); __syncthreads(); }
        float m = red[0];
        __syncthreads();
        float p0 = __expf(v0 - m);
        float p1 = (i1 < 511) ? __expf(v1 - m) : 0.f;
        red[t] = p0 + p1;
        __syncthreads();
        for (int s = 128; s > 0; s >>= 1) { if (t < s) red[t] += red[t + s]; __syncthreads(); }
        float inv = 1.0f / red[0];
        out[bb * 511 + t] = p0 * inv;
        if (i1 < 511) out[bb * 511 + i1] = p1 * inv;
    }
}

extern "C" void kernel_launch(void* const* d_in, const int* in_sizes, int n_in,
                              void* d_out, int out_size, void* d_ws, size_t ws_size,
                              hipStream_t stream) {
    const float* nf    = (const float*)d_in[0];
    const float* ef    = (const float*)d_in[1];
    const int*   nm    = (const int*)d_in[2];
    const int*   em    = (const int*)d_in[3];
    const float* npw   = (const float*)d_in[4];
    const float* npb   = (const float*)d_in[5];
    const float* epw   = (const float*)d_in[6];
    const float* epb   = (const float*)d_in[7];
    const float* wq    = (const float*)d_in[8];
    const float* wk    = (const float*)d_in[9];
    const float* wv    = (const float*)d_in[10];
    const float* eb1w  = (const float*)d_in[11];
    const float* eb1b  = (const float*)d_in[12];
    const float* eblng = (const float*)d_in[13];
    const float* eblnb = (const float*)d_in[14];
    const float* eb2w  = (const float*)d_in[15];
    const float* eb2b  = (const float*)d_in[16];
    const float* s1wv  = (const float*)d_in[17];
    const float* s1bv  = (const float*)d_in[18];
    const float* s2wv  = (const float*)d_in[19];
    const float* s2bv  = (const float*)d_in[20];
    const float* wow   = (const float*)d_in[21];
    const float* wob   = (const float*)d_in[22];
    const float* ln1g  = (const float*)d_in[23];
    const float* ln1b  = (const float*)d_in[24];
    const float* ln2g  = (const float*)d_in[25];
    const float* ln2b  = (const float*)d_in[26];
    const float* f1w   = (const float*)d_in[27];
    const float* f1b   = (const float*)d_in[28];
    const float* f2w   = (const float*)d_in[29];
    const float* f2b   = (const float*)d_in[30];
    const float* sc1w  = (const float*)d_in[31];
    const float* sc1b  = (const float*)d_in[32];
    const float* sclng = (const float*)d_in[33];
    const float* sclnb = (const float*)d_in[34];
    const float* sc2w  = (const float*)d_in[35];
    const float* sc2b  = (const float*)d_in[36];

    char* W = (char*)d_ws;
    u32*   bar    = (u32*)(W + 0);              //     4,096 B (zeroed)
    u64*   adj    = (u64*)(W + 4096);           //   131,072 B
    float* KT0    = (float*)(W + 135168);       //   524,288 B
    float* VT0    = (float*)(W + 659456);       //   524,288 B
    float* KT1    = (float*)(W + 1183744);      //   524,288 B
    float* VT1    = (float*)(W + 1708032);      //   524,288 B
    float* hbuf   = (float*)(W + 2232320);      //   524,288 B
    float* logits = (float*)(W + 2756608);      //     8,192 B
    float* vals   = (float*)(W + 2764800);      // 9,437,184 B [12][2048*96]

    float* out = (float*)d_out;                 // [probs 2044][h 131072]

    hipMemsetAsync(bar, 0, 4096, stream);
    hipLaunchKernelGGL(k_mega, dim3(NBLK), dim3(256), 0, stream,
        nf, ef, nm, em, npw, npb, epw, epb, wq, wk, wv,
        eb1w, eb1b, eblng, eblnb, eb2w, eb2b,
        s1wv, s1bv, s2wv, s2bv, wow, wob,
        ln1g, ln1b, ln2g, ln2b, f1w, f1b, f2w, f2b,
        sc1w, sc1b, sclng, sclnb, sc2w, sc2b,
        bar, adj, vals, KT0, VT0, KT1, VT1, hbuf, logits, out);
}

// Round 3
// 336.833 us; speedup vs baseline: 2.4650x; 1.8078x over previous
//
#include <hip/hip_runtime.h>
#include <math.h>

typedef unsigned long long u64;
typedef unsigned int u32;

// ---------------- wave helpers ----------------
__device__ __forceinline__ float wsum(float x) {
#pragma unroll
    for (int o = 1; o < 64; o <<= 1) x += __shfl_xor(x, o);
    return x;
}
__device__ __forceinline__ float wmaxr(float x) {
#pragma unroll
    for (int o = 1; o < 64; o <<= 1) x = fmaxf(x, __shfl_xor(x, o));
    return x;
}

// =================== kA: adjacency + per-row edge list + node projection ===================
// grid 512 x 256 : wave per row (4 rows/block)
__global__ __launch_bounds__(256) void kA(
    const int* __restrict__ em, const float* __restrict__ nf,
    const float* __restrict__ npw, const float* __restrict__ npb,
    u64* __restrict__ adj, u32* __restrict__ elist, u32* __restrict__ rowCnt,
    float* __restrict__ hbuf)
{
    int t = threadIdx.x, wv = t >> 6, lane = t & 63;
    int g = blockIdx.x * 4 + wv;                 // row 0..2047
    const int* emr = em + (size_t)g * 512;
    u32 run = 0;
#pragma unroll
    for (int s = 0; s < 8; ++s) {
        int j = s * 64 + lane;
        int v = emr[j];
        u64 bal = __ballot(v != 0);
        if (v != 0) {
            u32 slot = run + (u32)__popcll(bal & ((1ULL << lane) - 1ULL));
            if (slot < 96u) elist[g * 96 + slot] = (u32)j;
        }
        if (lane == 0) adj[(size_t)g * 8 + s] = bal;
        run += (u32)__popcll(bal);
    }
    if (lane == 0) rowCnt[g] = run < 96u ? run : 96u;
    // node projection
    float acc = npb[lane];
    const float* r = nf + (size_t)g * 18;
#pragma unroll
    for (int c = 0; c < 18; ++c) acc += r[c] * npw[c * 64 + lane];
    hbuf[(size_t)g * 64 + lane] = acc;
}

// =================== kB: BFS + edge-bias MLP (all 3 layers) + qkv(l=0) ===================
// grid 512 x 256 : wave per row
__global__ __launch_bounds__(256) void kB(
    const u64* __restrict__ adj, const float* __restrict__ ef,
    const u32* __restrict__ elist, const u32* __restrict__ rowCnt,
    const float* __restrict__ hbuf,
    const float* __restrict__ epw, const float* __restrict__ epb,
    const float* __restrict__ eb1w, const float* __restrict__ eb1b,
    const float* __restrict__ eblng, const float* __restrict__ eblnb,
    const float* __restrict__ eb2w, const float* __restrict__ eb2b,
    const float* __restrict__ wq, const float* __restrict__ wk, const float* __restrict__ wvw,
    unsigned char* __restrict__ spd, float* __restrict__ vals,
    float* __restrict__ Qb, float* __restrict__ KT, float* __restrict__ VT)
{
    __shared__ u64 adjL[4096 + 4 * 88];          // 32KB adj + per-wave BFS scratch
    int t = threadIdx.x, wv = t >> 6, lane = t & 63;
    int g = blockIdx.x * 4 + wv;
    int b = g >> 9, srow = g & 511;
    // stage batch adjacency (32 KB)
    {
        const float4* s = (const float4*)(adj + (size_t)b * 4096);
        float4* d = (float4*)adjL;
#pragma unroll
        for (int u = 0; u < 8; ++u) d[t + u * 256] = s[t + u * 256];
    }
    __syncthreads();
    // ---- BFS (one source row per wave) ----
    u64* wb = adjL + 4096 + wv * 88;
    u64* vis = wb; u64* fro = wb + 8; u64* nxt = wb + 16; u64* dist8 = wb + 24;
    unsigned char* dist = (unsigned char*)dist8;
    dist8[lane] = 0x0A0A0A0A0A0A0A0AULL;
    if (lane < 8) { vis[lane] = 0ULL; fro[lane] = 0ULL; nxt[lane] = 0ULL; }
    __syncthreads();
    if (lane == 0) {
        dist[srow] = 0;
        vis[srow >> 6] = 1ULL << (srow & 63);
        fro[srow >> 6] = 1ULL << (srow & 63);
    }
    __syncthreads();
    for (int d = 1; d <= 9; ++d) {
        int c = lane >> 3, w = lane & 7;
        u64 f = fro[c];
        u64 acc = 0ULL;
        while (f) {
            int k = (c << 6) + __builtin_ctzll(f);
            f &= f - 1;
            acc |= adjL[k * 8 + w];
        }
        if (acc) atomicOr(&nxt[w], acc);
        __syncthreads();
        if (lane < 8) {
            u64 nw = nxt[lane] & ~vis[lane];
            vis[lane] |= nw; fro[lane] = nw; nxt[lane] = 0ULL;
            while (nw) {
                int j = (lane << 6) + __builtin_ctzll(nw);
                nw &= nw - 1;
                dist[j] = (unsigned char)d;
            }
        }
        __syncthreads();
    }
    ((u64*)(spd + (size_t)g * 512))[lane] = dist8[lane];
    // ---- qkv layer 0 (own row; h broadcast via shfl) ----
    {
        float hv = hbuf[(size_t)g * 64 + lane];
        float aq = 0.f, ak = 0.f, av = 0.f;
        for (int k = 0; k < 64; ++k) {
            float hk = __shfl(hv, k);
            aq += hk * wq[k * 64 + lane];
            ak += hk * wk[k * 64 + lane];
            av += hk * wvw[k * 64 + lane];
        }
        Qb[(size_t)g * 64 + lane] = aq;
        KT[((size_t)(b * 64 + lane)) * 512 + srow] = ak;
        VT[((size_t)(b * 64 + lane)) * 512 + srow] = av;
    }
    // ---- edge-bias MLP (own row; edge projection shared across 3 layers) ----
    {
        u32 cnt = rowCnt[g];
        for (u32 s = lane; s < cnt; s += 64u) {
            u32 j = elist[g * 96 + s];
            const float* e7 = ef + ((size_t)g * 512 + j) * 7;
            float f0 = e7[0], f1 = e7[1], f2 = e7[2], f3 = e7[3], f4 = e7[4], f5 = e7[5], f6 = e7[6];
            float tt[3][16];
#pragma unroll
            for (int l = 0; l < 3; ++l)
#pragma unroll
                for (int c = 0; c < 16; ++c) tt[l][c] = eb1b[l * 16 + c];
            for (int k = 0; k < 64; ++k) {
                float ek = epb[k] + f0 * epw[k] + f1 * epw[64 + k] + f2 * epw[128 + k]
                         + f3 * epw[192 + k] + f4 * epw[256 + k] + f5 * epw[320 + k]
                         + f6 * epw[384 + k];
#pragma unroll
                for (int l = 0; l < 3; ++l) {
                    const float* W1 = eb1w + l * 1024 + k * 16;
#pragma unroll
                    for (int c = 0; c < 16; ++c) tt[l][c] += ek * W1[c];
                }
            }
#pragma unroll
            for (int l = 0; l < 3; ++l) {
                float m = 0.f;
#pragma unroll
                for (int c = 0; c < 16; ++c) m += tt[l][c];
                m *= 0.0625f;
                float var = 0.f;
#pragma unroll
                for (int c = 0; c < 16; ++c) { float d = tt[l][c] - m; var += d * d; }
                var *= 0.0625f;
                float inv = rsqrtf(var + 1e-5f);
#pragma unroll
                for (int c = 0; c < 16; ++c) {
                    float x = (tt[l][c] - m) * inv * eblng[l * 16 + c] + eblnb[l * 16 + c];
                    tt[l][c] = x >= 0.f ? x : 0.2f * x;
                }
#pragma unroll
                for (int hh = 0; hh < 4; ++hh) {
                    float a = eb2b[l * 4 + hh];
#pragma unroll
                    for (int c = 0; c < 16; ++c) a += tt[l][c] * eb2w[(l * 16 + c) * 4 + hh];
                    vals[(u32)(l * 4 + hh) * 196608u + (u32)g * 96u + s] = a;
                }
            }
        }
    }
}

// =================== kL: attention (4 heads) + oproj/LN1 + FFN/LN2 + qkv(l+1) ===================
// grid 512 x 256 : block per 4 rows, wave per row
__global__ __launch_bounds__(256, 2) void kL(
    const float* __restrict__ Qb, const float* __restrict__ KTin, const float* __restrict__ VTin,
    const unsigned char* __restrict__ spd, const u32* __restrict__ elist,
    const u32* __restrict__ rowCnt, const float* __restrict__ vals,
    const float* __restrict__ s1w, const float* __restrict__ s1b,
    const float* __restrict__ s2w, const float* __restrict__ s2b,
    const int* __restrict__ nm,
    const float* __restrict__ wow, const float* __restrict__ wob,
    const float* __restrict__ ln1g, const float* __restrict__ ln1b,
    const float* __restrict__ f1w, const float* __restrict__ f1b,
    const float* __restrict__ f2w, const float* __restrict__ f2b,
    const float* __restrict__ ln2g, const float* __restrict__ ln2b,
    const float* __restrict__ wqn, const float* __restrict__ wkn, const float* __restrict__ wvn,
    float* __restrict__ hbuf, float* __restrict__ QbOut,
    float* __restrict__ KTout, float* __restrict__ VTout,
    int l, float* __restrict__ out)
{
    __shared__ float kt[8192];                   // [16][512] K tile, then V tile
    __shared__ float bv[2048];                   // [4][512] bias tile / PV scratch
    __shared__ float ATTO[256];                  // [4][64]
    __shared__ unsigned char SPDl[2048];         // [4][512]
    int t = threadIdx.x, wv = t >> 6, lane = t & 63;
    int blk = blockIdx.x;
    int g = blk * 4 + wv;                        // own row
    int b = blk >> 7, srow = g & 511;
    float hv = hbuf[(size_t)g * 64 + lane];      // pre-layer h (residual)
    float qrow = Qb[(size_t)g * 64 + lane];
    // stage SPD rows (2 KB)
    {
        const u32* sp = (const u32*)(spd + (size_t)(blk * 4) * 512);
        u32* dd = (u32*)SPDl;
        dd[t] = sp[t]; dd[t + 256] = sp[t + 256];
    }
    // node-mask adds (hoisted)
    float madd[8];
#pragma unroll
    for (int c = 0; c < 8; ++c) madd[c] = (nm[b * 512 + c * 64 + lane] != 0) ? 0.f : -1e9f;
    // own-row edge indices (<=96, 2 per lane)
    u32 cnt = rowCnt[g];
    u32 ej0 = 0, ej1 = 0;
    if (lane < (int)cnt) ej0 = elist[g * 96 + lane];
    if (lane + 64 < (int)cnt) ej1 = elist[g * 96 + lane + 64];

#pragma unroll 1
    for (int hh = 0; hh < 4; ++hh) {
        __syncthreads();                         // prev head done with kt/bv
        // stage K tile (32 KB, plain cached loads)
        {
            const float4* s = (const float4*)(KTin + ((size_t)(b * 64 + hh * 16)) * 512);
            float4* d = (float4*)kt;
#pragma unroll
            for (int u = 0; u < 8; ++u) d[t + u * 256] = s[t + u * 256];
        }
        // spd-bias table in lane registers
        float tval;
        {
            int li = lane < 11 ? lane : 10;
            float x = (float)li * 0.1f;
            float a = s2b[l * 4 + hh];
#pragma unroll
            for (int c = 0; c < 16; ++c) {
                float v = x * s1w[l * 16 + c] + s1b[l * 16 + c];
                v = v >= 0.f ? v : 0.2f * v;
                a += v * s2w[(l * 16 + c) * 4 + hh];
            }
            tval = a;
        }
        // bias tile from SPD bytes
#pragma unroll
        for (int p = 0; p < 2; ++p) {
            int i32 = t + p * 256;
            u32 w4 = ((const u32*)SPDl)[i32];
            float4 bb;
            bb.x = __shfl(tval, (int)(w4 & 255u));
            bb.y = __shfl(tval, (int)((w4 >> 8) & 255u));
            bb.z = __shfl(tval, (int)((w4 >> 16) & 255u));
            bb.w = __shfl(tval, (int)(w4 >> 24));
            ((float4*)bv)[i32] = bb;
        }
        __syncthreads();                         // kt staged + bias init (cross-wave)
        // sparse edge overlay (own wave's row only -> no extra sync)
        u32 vp = (u32)(l * 4 + hh) * 196608u;
        if (lane < (int)cnt) bv[wv * 512 + (int)(ej0 & 511u)] = vals[vp + (u32)g * 96u + lane];
        if (lane + 64 < (int)cnt) bv[wv * 512 + (int)(ej1 & 511u)] = vals[vp + (u32)g * 96u + lane + 64];
        // Q fragment
        float q[16];
#pragma unroll
        for (int d = 0; d < 16; ++d) q[d] = __shfl(qrow, hh * 16 + d);
        // QK + bias + mask
        float sc[8];
        float mx = -3e38f;
#pragma unroll
        for (int c = 0; c < 8; ++c) {
            int j = c * 64 + lane;
            float s = 0.f;
#pragma unroll
            for (int d = 0; d < 16; ++d) s += q[d] * kt[d * 512 + j];
            s = s * 0.25f + bv[wv * 512 + j] + madd[c];
            sc[c] = s;
            mx = fmaxf(mx, s);
        }
        mx = wmaxr(mx);
        float sm = 0.f;
#pragma unroll
        for (int c = 0; c < 8; ++c) { sc[c] = __expf(sc[c] - mx); sm += sc[c]; }
        float sminv = 1.0f / wsum(sm);
#pragma unroll
        for (int c = 0; c < 8; ++c) sc[c] *= sminv;
        __syncthreads();                         // done reading kt(K) + bv(bias)
        // stage V tile over kt
        {
            const float4* s = (const float4*)(VTin + ((size_t)(b * 64 + hh * 16)) * 512);
            float4* d = (float4*)kt;
#pragma unroll
            for (int u = 0; u < 8; ++u) d[t + u * 256] = s[t + u * 256];
        }
        __syncthreads();
        // PV
        float acc[16];
#pragma unroll
        for (int d = 0; d < 16; ++d) acc[d] = 0.f;
#pragma unroll
        for (int c = 0; c < 8; ++c) {
            int j = c * 64 + lane;
#pragma unroll
            for (int d = 0; d < 16; ++d) acc[d] += sc[c] * kt[d * 512 + j];
        }
#pragma unroll
        for (int d = 0; d < 16; ++d) {
            acc[d] += __shfl_xor(acc[d], 16);
            acc[d] += __shfl_xor(acc[d], 32);
        }
        float* scr = bv + wv * 272;              // 16 x stride-17, wave-private
        if (lane < 16) {
#pragma unroll
            for (int d = 0; d < 16; ++d) scr[lane * 17 + d] = acc[d];
        }
        if (lane < 16) {
            float o = 0.f;
#pragma unroll
            for (int m = 0; m < 16; ++m) o += scr[m * 17 + lane];
            ATTO[wv * 64 + hh * 16 + lane] = o;
        }
    }
    // ---- output projection + residual + LN1 (ATTO row is wave-local) ----
    float h1;
    {
        float a = wob[l * 64 + lane];
        const float* Wo = wow + l * 4096;
        for (int k = 0; k < 64; ++k) a += ATTO[wv * 64 + k] * Wo[k * 64 + lane];
        float xx = a + hv;
        float mn = wsum(xx) * 0.015625f;
        float d = xx - mn;
        float var = wsum(d * d) * 0.015625f;
        h1 = d * rsqrtf(var + 1e-5f) * ln1g[l * 64 + lane] + ln1b[l * 64 + lane];
    }
    // ---- FFN + residual + LN2 (register/shuffle only) ----
    float hn;
    {
        const float* W1 = f1w + l * 16384;
        const float* W2 = f2w + l * 16384;
        float a1[4];
#pragma unroll
        for (int m = 0; m < 4; ++m) a1[m] = f1b[l * 256 + m * 64 + lane];
        for (int k = 0; k < 64; ++k) {
            float hk = __shfl(h1, k);
#pragma unroll
            for (int m = 0; m < 4; ++m) a1[m] += hk * W1[k * 256 + m * 64 + lane];
        }
        float ffv[4];
#pragma unroll
        for (int m = 0; m < 4; ++m) {
            float u = a1[m];
            ffv[m] = 0.5f * u * (1.0f + erff(u * 0.70710678118654752f));
        }
        float a2 = 0.f;
#pragma unroll 1
        for (int m = 0; m < 4; ++m) {
            for (int ll = 0; ll < 64; ++ll) {
                a2 += __shfl(ffv[m], ll) * W2[(m * 64 + ll) * 64 + lane];
            }
        }
        float xx = a2 + f2b[l * 64 + lane] + h1;
        float mn = wsum(xx) * 0.015625f;
        float d = xx - mn;
        float var = wsum(d * d) * 0.015625f;
        hn = d * rsqrtf(var + 1e-5f) * ln2g[l * 64 + lane] + ln2b[l * 64 + lane];
    }
    hbuf[(size_t)g * 64 + lane] = hn;
    if (l == 2) {
        out[2044 + (size_t)g * 64 + lane] = hn;
    } else {
        // ---- qkv for layer l+1 ----
        float aq = 0.f, ak = 0.f, av = 0.f;
        for (int k = 0; k < 64; ++k) {
            float hk = __shfl(hn, k);
            aq += hk * wqn[k * 64 + lane];
            ak += hk * wkn[k * 64 + lane];
            av += hk * wvn[k * 64 + lane];
        }
        QbOut[(size_t)g * 64 + lane] = aq;
        KTout[((size_t)(b * 64 + lane)) * 512 + srow] = ak;
        VTout[((size_t)(b * 64 + lane)) * 512 + srow] = av;
    }
}

// =================== kS: scoring head ===================
// grid 512 x 256 : wave per candidate
__global__ __launch_bounds__(256) void kS(
    const float* __restrict__ hbuf,
    const float* __restrict__ s1w, const float* __restrict__ s1b,
    const float* __restrict__ lng, const float* __restrict__ lnb,
    const float* __restrict__ s2w, const float* __restrict__ s2b,
    float* __restrict__ logits)
{
    int t = threadIdx.x, wv = t >> 6, lane = t & 63;
    int wid = blockIdx.x * 4 + wv;               // 0..2047
    if (wid >= 2044) return;
    int bb = wid / 511; int jj = wid % 511; int j = jj + 1;
    float ego = hbuf[(size_t)bb * 32768 + lane];
    float cand = hbuf[((size_t)(bb * 512 + j)) * 64 + lane];
    float acc = s1b[lane];
    for (int k = 0; k < 64; ++k) acc += __shfl(ego, k) * s1w[k * 64 + lane];
    for (int k = 0; k < 64; ++k) acc += __shfl(cand, k) * s1w[(64 + k) * 64 + lane];
    float mn = wsum(acc) * 0.015625f;
    float d = acc - mn;
    float var = wsum(d * d) * 0.015625f;
    float x = d * rsqrtf(var + 1e-5f) * lng[lane] + lnb[lane];
    x = x >= 0.f ? x : 0.2f * x;
    float p = wsum(x * s2w[lane]);
    if (lane == 0) logits[wid] = p + s2b[0];
}

// =================== kP: final softmax over candidates ===================
// grid 4 x 512
__global__ __launch_bounds__(512) void kP(
    const float* __restrict__ logits, const int* __restrict__ nmask, float* __restrict__ out)
{
    __shared__ float red[512];
    __shared__ int anyf;
    int b = blockIdx.x; int t = threadIdx.x;
    bool cand = false;
    if (t < 511) cand = nmask[b * 512 + 1 + t] != 0;
    if (t == 0) anyf = 0;
    __syncthreads();
    if (cand) atomicOr(&anyf, 1);
    __syncthreads();
    if (t == 0 && anyf == 0) cand = true;
    float val = -3e38f;
    if (t < 511) val = cand ? logits[b * 511 + t] : -1e9f;
    red[t] = val; __syncthreads();
    for (int s = 256; s > 0; s >>= 1) { if (t < s) red[t] = fmaxf(red[t], red[t + s]); __syncthreads(); }
    float m = red[0]; __syncthreads();
    float p = (t < 511) ? __expf(val - m) : 0.f;
    red[t] = p; __syncthreads();
    for (int s = 256; s > 0; s >>= 1) { if (t < s) red[t] += red[t + s]; __syncthreads(); }
    float inv = 1.0f / red[0];
    if (t < 511) out[b * 511 + t] = p * inv;
}

extern "C" void kernel_launch(void* const* d_in, const int* in_sizes, int n_in,
                              void* d_out, int out_size, void* d_ws, size_t ws_size,
                              hipStream_t stream) {
    const float* nf    = (const float*)d_in[0];
    const float* ef    = (const float*)d_in[1];
    const int*   nm    = (const int*)d_in[2];
    const int*   em    = (const int*)d_in[3];
    const float* npw   = (const float*)d_in[4];
    const float* npb   = (const float*)d_in[5];
    const float* epw   = (const float*)d_in[6];
    const float* epb   = (const float*)d_in[7];
    const float* wq    = (const float*)d_in[8];
    const float* wk    = (const float*)d_in[9];
    const float* wv    = (const float*)d_in[10];
    const float* eb1w  = (const float*)d_in[11];
    const float* eb1b  = (const float*)d_in[12];
    const float* eblng = (const float*)d_in[13];
    const float* eblnb = (const float*)d_in[14];
    const float* eb2w  = (const float*)d_in[15];
    const float* eb2b  = (const float*)d_in[16];
    const float* s1wv  = (const float*)d_in[17];
    const float* s1bv  = (const float*)d_in[18];
    const float* s2wv  = (const float*)d_in[19];
    const float* s2bv  = (const float*)d_in[20];
    const float* wow   = (const float*)d_in[21];
    const float* wob   = (const float*)d_in[22];
    const float* ln1g  = (const float*)d_in[23];
    const float* ln1b  = (const float*)d_in[24];
    const float* ln2g  = (const float*)d_in[25];
    const float* ln2b  = (const float*)d_in[26];
    const float* f1w   = (const float*)d_in[27];
    const float* f1b   = (const float*)d_in[28];
    const float* f2w   = (const float*)d_in[29];
    const float* f2b   = (const float*)d_in[30];
    const float* sc1w  = (const float*)d_in[31];
    const float* sc1b  = (const float*)d_in[32];
    const float* sclng = (const float*)d_in[33];
    const float* sclnb = (const float*)d_in[34];
    const float* sc2w  = (const float*)d_in[35];
    const float* sc2b  = (const float*)d_in[36];

    char* W = (char*)d_ws;
    u64*   adj    = (u64*)(W + 0);              //   131,072 B
    unsigned char* spd = (unsigned char*)(W + 131072);   // 1,048,576 B
    u32*   elist  = (u32*)(W + 1179648);        //   786,432 B [2048][96]
    u32*   rowCnt = (u32*)(W + 1966080);        //     8,192 B
    float* vals   = (float*)(W + 1974272);      // 9,437,184 B [12][2048*96]
    float* hbuf   = (float*)(W + 11411456);     //   524,288 B
    float* Qb     = (float*)(W + 11935744);     //   524,288 B
    float* KT0    = (float*)(W + 12460032);     //   524,288 B
    float* VT0    = (float*)(W + 12984320);     //   524,288 B
    float* KT1    = (float*)(W + 13508608);     //   524,288 B
    float* VT1    = (float*)(W + 14032896);     //   524,288 B
    float* logits = (float*)(W + 14557184);     //     8,192 B

    float* out = (float*)d_out;                 // [probs 2044][h 131072]

    kA<<<512, 256, 0, stream>>>(em, nf, npw, npb, adj, elist, rowCnt, hbuf);
    kB<<<512, 256, 0, stream>>>(adj, ef, elist, rowCnt, hbuf, epw, epb,
                                eb1w, eb1b, eblng, eblnb, eb2w, eb2b,
                                wq, wk, wv, spd, vals, Qb, KT0, VT0);
    kL<<<512, 256, 0, stream>>>(Qb, KT0, VT0, spd, elist, rowCnt, vals,
                                s1wv, s1bv, s2wv, s2bv, nm,
                                wow, wob, ln1g, ln1b, f1w, f1b, f2w, f2b, ln2g, ln2b,
                                wq + 4096, wk + 4096, wv + 4096,
                                hbuf, Qb, KT1, VT1, 0, out);
    kL<<<512, 256, 0, stream>>>(Qb, KT1, VT1, spd, elist, rowCnt, vals,
                                s1wv, s1bv, s2wv, s2bv, nm,
                                wow, wob, ln1g, ln1b, f1w, f1b, f2w, f2b, ln2g, ln2b,
                                wq + 8192, wk + 8192, wv + 8192,
                                hbuf, Qb, KT0, VT0, 1, out);
    kL<<<512, 256, 0, stream>>>(Qb, KT0, VT0, spd, elist, rowCnt, vals,
                                s1wv, s1bv, s2wv, s2bv, nm,
                                wow, wob, ln1g, ln1b, f1w, f1b, f2w, f2b, ln2g, ln2b,
                                wq, wk, wv,
                                hbuf, Qb, KT1, VT1, 2, out);
    kS<<<512, 256, 0, stream>>>(hbuf, sc1w, sc1b, sclng, sclnb, sc2w, sc2b, logits);
    kP<<<4, 512, 0, stream>>>(logits, nm, out);
}

// Round 4
// 315.765 us; speedup vs baseline: 2.6295x; 1.0667x over previous
//
#include <hip/hip_runtime.h>
#include <math.h>

typedef unsigned long long u64;
typedef unsigned int u32;

// ---------------- wave helpers ----------------
__device__ __forceinline__ float wsum(float x) {
#pragma unroll
    for (int o = 1; o < 64; o <<= 1) x += __shfl_xor(x, o);
    return x;
}
__device__ __forceinline__ float wmaxr(float x) {
#pragma unroll
    for (int o = 1; o < 64; o <<= 1) x = fmaxf(x, __shfl_xor(x, o));
    return x;
}

// =================== kA: adjacency + per-row edge list + node projection ===================
// grid 512 x 256 : wave per row
__global__ __launch_bounds__(256) void kA(
    const int* __restrict__ em, const float* __restrict__ nf,
    const float* __restrict__ npw, const float* __restrict__ npb,
    u64* __restrict__ adj, u32* __restrict__ elist, u32* __restrict__ rowCnt,
    float* __restrict__ hbuf)
{
    int t = threadIdx.x, wv = t >> 6, lane = t & 63;
    int g = blockIdx.x * 4 + wv;
    const int* emr = em + (size_t)g * 512;
    u32 run = 0;
#pragma unroll
    for (int s = 0; s < 8; ++s) {
        int j = s * 64 + lane;
        int v = emr[j];
        u64 bal = __ballot(v != 0);
        if (v != 0) {
            u32 slot = run + (u32)__popcll(bal & ((1ULL << lane) - 1ULL));
            if (slot < 96u) elist[g * 96 + slot] = (u32)j;
        }
        if (lane == 0) adj[(size_t)g * 8 + s] = bal;
        run += (u32)__popcll(bal);
    }
    if (lane == 0) rowCnt[g] = run < 96u ? run : 96u;
    float acc = npb[lane];
    const float* r = nf + (size_t)g * 18;
#pragma unroll
    for (int c = 0; c < 18; ++c) acc += r[c] * npw[c * 64 + lane];
    hbuf[(size_t)g * 64 + lane] = acc;
}

// =================== kB: BFS (early-exit) + factored edge-MLP + qkv(l=0) ===================
// grid 512 x 256 : wave per row
__global__ __launch_bounds__(256) void kB(
    const u64* __restrict__ adj, const float* __restrict__ ef,
    const u32* __restrict__ elist, const u32* __restrict__ rowCnt,
    const float* __restrict__ hbuf,
    const float* __restrict__ epw, const float* __restrict__ epb,
    const float* __restrict__ eb1w, const float* __restrict__ eb1b,
    const float* __restrict__ eblng, const float* __restrict__ eblnb,
    const float* __restrict__ eb2w, const float* __restrict__ eb2b,
    const float* __restrict__ wq, const float* __restrict__ wk, const float* __restrict__ wvw,
    unsigned char* __restrict__ spd, float* __restrict__ vals,
    float* __restrict__ Qb, float* __restrict__ KT, float* __restrict__ VT)
{
    __shared__ u64 adjL[4096];                   // 32 KB batch adjacency
    __shared__ u64 bfsS[4][24];                  // per-wave vis/fro/nxt
    __shared__ float MS[684];                    // M[3][8][16] | eb2w 192 | lng 48 | lnb 48 | eb2b 12
    __shared__ u32 pool[384];
    __shared__ u32 offs[5];
    __shared__ u32 cA[4];
    __shared__ int votes[4];
    int t = threadIdx.x, wv = t >> 6, lane = t & 63;
    int g = blockIdx.x * 4 + wv;
    int b = g >> 9, srow = g & 511;
    // stage batch adjacency
    {
        const float4* s = (const float4*)(adj + (size_t)b * 4096);
        float4* d = (float4*)adjL;
#pragma unroll
        for (int u = 0; u < 8; ++u) d[t + u * 256] = s[t + u * 256];
    }
    // precompute M = epw ∘ eb1w (folded bias in row 7) + stage small params
    for (int u = t; u < 384; u += 256) {
        int l = u >> 7, r = u & 127, f = r >> 4, c = r & 15;
        const float* W1 = eb1w + l * 1024 + c;
        float s;
        if (f < 7) {
            s = 0.f;
            const float* ew = epw + f * 64;
            for (int k = 0; k < 64; ++k) s += ew[k] * W1[k * 16];
        } else {
            s = eb1b[l * 16 + c];
            for (int k = 0; k < 64; ++k) s += epb[k] * W1[k * 16];
        }
        MS[u] = s;
    }
    if (t < 192) MS[384 + t] = eb2w[t];
    if (t < 48) { MS[576 + t] = eblng[t]; MS[624 + t] = eblnb[t]; }
    if (t < 12) MS[672 + t] = eb2b[t];
    u64* vis = &bfsS[wv][0]; u64* fro = vis + 8; u64* nxt = vis + 16;
    if (lane < 8) {
        u64 iv = (lane == (srow >> 6)) ? (1ULL << (srow & 63)) : 0ULL;
        vis[lane] = iv; fro[lane] = iv; nxt[lane] = 0ULL;
    }
    __syncthreads();
    // ---- BFS: dist bytes in per-lane register, early exit on empty frontier ----
    u64 myDist = 0x0A0A0A0A0A0A0A0AULL;
    if (lane == (srow >> 3)) myDist &= ~(0xFFULL << ((srow & 7) * 8));
    for (int d = 1; d <= 9; ++d) {
        int c = lane >> 3, w = lane & 7;
        u64 f = fro[c];
        u64 acc = 0ULL;
        while (f) {
            int k = (c << 6) + __builtin_ctzll(f);
            f &= f - 1;
            acc |= adjL[k * 8 + w];
        }
        if (acc) atomicOr(&nxt[w], acc);
        __syncthreads();
        u64 nw = 0ULL;
        if (lane < 8) {
            nw = nxt[lane] & ~vis[lane];
            vis[lane] |= nw; fro[lane] = nw; nxt[lane] = 0ULL;
        }
        u64 bal = __ballot(nw != 0ULL);
        if (lane == 0) votes[wv] = (bal != 0ULL) ? 1 : 0;
        __syncthreads();
        u64 fw = fro[lane >> 3];
        u32 bits = (u32)(fw >> ((lane & 7) * 8)) & 0xFFu;
        if (bits) {
            u64 bm = 0ULL;
#pragma unroll
            for (int kk = 0; kk < 8; ++kk) if (bits & (1u << kk)) bm |= 0xFFULL << (8 * kk);
            myDist = (myDist & ~bm) | ((0x0101010101010101ULL * (u64)(u32)d) & bm);
        }
        if (!(votes[0] | votes[1] | votes[2] | votes[3])) break;
    }
    ((u64*)spd)[(size_t)g * 64 + lane] = myDist;
    // ---- qkv layer 0 (own row) ----
    {
        float hv = hbuf[(size_t)g * 64 + lane];
        float aq = 0.f, ak = 0.f, av = 0.f;
        for (int k = 0; k < 64; ++k) {
            float hk = __shfl(hv, k);
            aq += hk * wq[k * 64 + lane];
            ak += hk * wk[k * 64 + lane];
            av += hk * wvw[k * 64 + lane];
        }
        Qb[(size_t)g * 64 + lane] = aq;
        KT[((size_t)(b * 64 + lane)) * 512 + srow] = ak;
        VT[((size_t)(b * 64 + lane)) * 512 + srow] = av;
    }
    // ---- pool the block's edges, then factored MLP (thread per edge) ----
    u32 cnt = rowCnt[g];
    if (lane == 0) cA[wv] = cnt;
    __syncthreads();
    if (t == 0) {
        u32 a = 0;
        for (int i = 0; i < 4; ++i) { offs[i] = a; a += cA[i]; }
        offs[4] = a;
    }
    __syncthreads();
    u32 base = offs[wv];
    if (lane < (int)cnt)
        pool[base + lane] = ((u32)wv << 16) | ((u32)lane << 9) | elist[g * 96 + lane];
    if (lane + 64 < (int)cnt)
        pool[base + lane + 64] = ((u32)wv << 16) | ((u32)(lane + 64) << 9) | elist[g * 96 + lane + 64];
    __syncthreads();
    u32 tot = offs[4];
    for (u32 e = t; e < tot; e += 256) {
        u32 p = pool[e];
        int rl = (int)(p >> 16);
        u32 s = (p >> 9) & 127u;
        u32 j = p & 511u;
        int ge = blockIdx.x * 4 + rl;
        const float* e7 = ef + ((size_t)ge * 512 + j) * 7;
        float ff[7];
#pragma unroll
        for (int f = 0; f < 7; ++f) ff[f] = e7[f];
#pragma unroll 1
        for (int l = 0; l < 3; ++l) {
            float tt[16];
#pragma unroll
            for (int c = 0; c < 16; ++c) tt[c] = MS[(l * 8 + 7) * 16 + c];
#pragma unroll
            for (int f = 0; f < 7; ++f) {
                float fv = ff[f];
#pragma unroll
                for (int c = 0; c < 16; ++c) tt[c] += fv * MS[(l * 8 + f) * 16 + c];
            }
            float m = 0.f;
#pragma unroll
            for (int c = 0; c < 16; ++c) m += tt[c];
            m *= 0.0625f;
            float var = 0.f;
#pragma unroll
            for (int c = 0; c < 16; ++c) { float d = tt[c] - m; var += d * d; }
            var *= 0.0625f;
            float inv = rsqrtf(var + 1e-5f);
#pragma unroll
            for (int c = 0; c < 16; ++c) {
                float x = (tt[c] - m) * inv * MS[576 + l * 16 + c] + MS[624 + l * 16 + c];
                tt[c] = x >= 0.f ? x : 0.2f * x;
            }
#pragma unroll
            for (int hh = 0; hh < 4; ++hh) {
                float a = MS[672 + l * 4 + hh];
#pragma unroll
                for (int c = 0; c < 16; ++c) a += tt[c] * MS[384 + (l * 16 + c) * 4 + hh];
                vals[(u32)(l * 4 + hh) * 196608u + (u32)ge * 96u + s] = a;
            }
        }
    }
}

// =================== kAttn: one (b,head) x 4 rows per block ===================
// grid 2048 x 256 : bh = blk>>7, 4-row tile = blk&127, wave per row
__global__ __launch_bounds__(256) void kAttn(
    const float* __restrict__ Qb, const float* __restrict__ KTin, const float* __restrict__ VTin,
    const unsigned char* __restrict__ spd, const u32* __restrict__ elist,
    const u32* __restrict__ rowCnt, const float* __restrict__ vals,
    const float* __restrict__ s1w, const float* __restrict__ s1b,
    const float* __restrict__ s2w, const float* __restrict__ s2b,
    const int* __restrict__ nm, int l, float* __restrict__ attO)
{
    __shared__ float kt[8192];                   // [16][512] K tile, then V tile
    __shared__ float bv[2048];                   // [4][512] bias / PV scratch
    int t = threadIdx.x, wv = t >> 6, lane = t & 63;
    int blk = blockIdx.x;
    int bh = blk >> 7, tile = blk & 127;
    int b = bh >> 2, hh = bh & 3;
    int rbase = tile * 4;
    int g = b * 512 + rbase + wv;                // global row
    // stage K tile
    {
        const float4* s = (const float4*)(KTin + ((size_t)(b * 64 + hh * 16)) * 512);
        float4* d = (float4*)kt;
#pragma unroll
        for (int u = 0; u < 8; ++u) d[t + u * 256] = s[t + u * 256];
    }
    // spd-bias table in lane registers
    float tval;
    {
        int li = lane < 11 ? lane : 10;
        float x = (float)li * 0.1f;
        float a = s2b[l * 4 + hh];
#pragma unroll
        for (int c = 0; c < 16; ++c) {
            float v = x * s1w[l * 16 + c] + s1b[l * 16 + c];
            v = v >= 0.f ? v : 0.2f * v;
            a += v * s2w[(l * 16 + c) * 4 + hh];
        }
        tval = a;
    }
    // bias tile from spd bytes (each thread decodes the words it loads)
    {
        const u32* sp = (const u32*)(spd + ((size_t)(b * 512 + rbase)) * 512);
#pragma unroll
        for (int p = 0; p < 2; ++p) {
            int i32 = t + p * 256;
            u32 w4 = sp[i32];
            float4 bb;
            bb.x = __shfl(tval, (int)(w4 & 255u));
            bb.y = __shfl(tval, (int)((w4 >> 8) & 255u));
            bb.z = __shfl(tval, (int)((w4 >> 16) & 255u));
            bb.w = __shfl(tval, (int)(w4 >> 24));
            ((float4*)bv)[i32] = bb;
        }
    }
    __syncthreads();                             // kt + bv ready (cross-wave)
    // sparse edge overlay (own row)
    u32 cnt = rowCnt[g];
    u32 vp = (u32)(l * 4 + hh) * 196608u;
    if (lane < (int)cnt) {
        u32 j = elist[g * 96 + lane];
        bv[wv * 512 + j] = vals[vp + (u32)g * 96u + lane];
    }
    if (lane + 64 < (int)cnt) {
        u32 j = elist[g * 96 + lane + 64];
        bv[wv * 512 + j] = vals[vp + (u32)g * 96u + lane + 64];
    }
    // node mask
    float madd[8];
#pragma unroll
    for (int c = 0; c < 8; ++c) madd[c] = (nm[b * 512 + c * 64 + lane] != 0) ? 0.f : -1e9f;
    // Q fragment
    float qrow = Qb[(size_t)g * 64 + lane];
    float q[16];
#pragma unroll
    for (int d = 0; d < 16; ++d) q[d] = __shfl(qrow, hh * 16 + d);
    // QK + bias + mask + softmax
    float sc[8];
    float mx = -3e38f;
#pragma unroll
    for (int c = 0; c < 8; ++c) {
        int j = c * 64 + lane;
        float s = 0.f;
#pragma unroll
        for (int d = 0; d < 16; ++d) s += q[d] * kt[d * 512 + j];
        s = s * 0.25f + bv[wv * 512 + j] + madd[c];
        sc[c] = s;
        mx = fmaxf(mx, s);
    }
    mx = wmaxr(mx);
    float sm = 0.f;
#pragma unroll
    for (int c = 0; c < 8; ++c) { sc[c] = __expf(sc[c] - mx); sm += sc[c]; }
    float sminv = 1.0f / wsum(sm);
#pragma unroll
    for (int c = 0; c < 8; ++c) sc[c] *= sminv;
    __syncthreads();                             // all waves done with K + bias
    // stage V tile
    {
        const float4* s = (const float4*)(VTin + ((size_t)(b * 64 + hh * 16)) * 512);
        float4* d = (float4*)kt;
#pragma unroll
        for (int u = 0; u < 8; ++u) d[t + u * 256] = s[t + u * 256];
    }
    __syncthreads();
    // PV
    float acc[16];
#pragma unroll
    for (int d = 0; d < 16; ++d) acc[d] = 0.f;
#pragma unroll
    for (int c = 0; c < 8; ++c) {
        int j = c * 64 + lane;
#pragma unroll
        for (int d = 0; d < 16; ++d) acc[d] += sc[c] * kt[d * 512 + j];
    }
#pragma unroll
    for (int d = 0; d < 16; ++d) {
        acc[d] += __shfl_xor(acc[d], 16);
        acc[d] += __shfl_xor(acc[d], 32);
    }
    float* scr = bv + wv * 272;                  // wave-private 16 x stride-17
    if (lane < 16) {
#pragma unroll
        for (int d = 0; d < 16; ++d) scr[lane * 17 + d] = acc[d];
    }
    if (lane < 16) {
        float o = 0.f;
#pragma unroll
        for (int m = 0; m < 16; ++m) o += scr[m * 17 + lane];
        attO[(size_t)g * 64 + hh * 16 + lane] = o;
    }
}

// =================== kLF: oproj + LN1 + FFN + LN2 + qkv(l+1) [+ egoAcc at l=2] ===================
// grid 512 x 256 : wave per row
__global__ __launch_bounds__(256) void kLF(
    const float* __restrict__ attO,
    const float* __restrict__ wow, const float* __restrict__ wob,
    const float* __restrict__ ln1g, const float* __restrict__ ln1b,
    const float* __restrict__ f1w, const float* __restrict__ f1b,
    const float* __restrict__ f2w, const float* __restrict__ f2b,
    const float* __restrict__ ln2g, const float* __restrict__ ln2b,
    const float* __restrict__ wqn, const float* __restrict__ wkn, const float* __restrict__ wvn,
    const float* __restrict__ sc1w, const float* __restrict__ sc1b,
    float* __restrict__ hbuf, float* __restrict__ QbOut,
    float* __restrict__ KTout, float* __restrict__ VTout,
    float* __restrict__ egoAcc, int l, float* __restrict__ out)
{
    int t = threadIdx.x, wv = t >> 6, lane = t & 63;
    int g = blockIdx.x * 4 + wv;
    int b = g >> 9, srow = g & 511;
    float hv = hbuf[(size_t)g * 64 + lane];
    float att = attO[(size_t)g * 64 + lane];
    // oproj + residual + LN1
    float h1;
    {
        float a = wob[l * 64 + lane];
        const float* Wo = wow + l * 4096;
        for (int k = 0; k < 64; ++k) a += __shfl(att, k) * Wo[k * 64 + lane];
        float xx = a + hv;
        float mn = wsum(xx) * 0.015625f;
        float d = xx - mn;
        float var = wsum(d * d) * 0.015625f;
        h1 = d * rsqrtf(var + 1e-5f) * ln1g[l * 64 + lane] + ln1b[l * 64 + lane];
    }
    // FFN + residual + LN2
    float hn;
    {
        const float* W1 = f1w + l * 16384;
        const float* W2 = f2w + l * 16384;
        float a1[4];
#pragma unroll
        for (int m = 0; m < 4; ++m) a1[m] = f1b[l * 256 + m * 64 + lane];
        for (int k = 0; k < 64; ++k) {
            float hk = __shfl(h1, k);
#pragma unroll
            for (int m = 0; m < 4; ++m) a1[m] += hk * W1[k * 256 + m * 64 + lane];
        }
        float ffv[4];
#pragma unroll
        for (int m = 0; m < 4; ++m) {
            float u = a1[m];
            ffv[m] = 0.5f * u * (1.0f + erff(u * 0.70710678118654752f));
        }
        float a2 = 0.f;
#pragma unroll 1
        for (int m = 0; m < 4; ++m) {
            for (int ll = 0; ll < 64; ++ll) {
                a2 += __shfl(ffv[m], ll) * W2[(m * 64 + ll) * 64 + lane];
            }
        }
        float xx = a2 + f2b[l * 64 + lane] + h1;
        float mn = wsum(xx) * 0.015625f;
        float d = xx - mn;
        float var = wsum(d * d) * 0.015625f;
        hn = d * rsqrtf(var + 1e-5f) * ln2g[l * 64 + lane] + ln2b[l * 64 + lane];
    }
    hbuf[(size_t)g * 64 + lane] = hn;
    if (l == 2) {
        out[2044 + (size_t)g * 64 + lane] = hn;
        if (srow == 0) {
            float ea = sc1b[lane];
            for (int k = 0; k < 64; ++k) ea += __shfl(hn, k) * sc1w[k * 64 + lane];
            egoAcc[b * 64 + lane] = ea;
        }
    } else {
        float aq = 0.f, ak = 0.f, av = 0.f;
        for (int k = 0; k < 64; ++k) {
            float hk = __shfl(hn, k);
            aq += hk * wqn[k * 64 + lane];
            ak += hk * wkn[k * 64 + lane];
            av += hk * wvn[k * 64 + lane];
        }
        QbOut[(size_t)g * 64 + lane] = aq;
        KTout[((size_t)(b * 64 + lane)) * 512 + srow] = ak;
        VTout[((size_t)(b * 64 + lane)) * 512 + srow] = av;
    }
}

// =================== kS: scoring head (ego half precomputed) ===================
// grid 511 x 256 : wave per candidate
__global__ __launch_bounds__(256) void kS(
    const float* __restrict__ hbuf, const float* __restrict__ egoAcc,
    const float* __restrict__ s1w,
    const float* __restrict__ lng, const float* __restrict__ lnb,
    const float* __restrict__ s2w, const float* __restrict__ s2b,
    float* __restrict__ logits)
{
    int t = threadIdx.x, wv = t >> 6, lane = t & 63;
    int wid = blockIdx.x * 4 + wv;               // 0..2043
    if (wid >= 2044) return;
    int bb = wid / 511; int jj = wid % 511; int j = jj + 1;
    float cand = hbuf[((size_t)(bb * 512 + j)) * 64 + lane];
    float acc = egoAcc[bb * 64 + lane];
    for (int k = 0; k < 64; ++k) acc += __shfl(cand, k) * s1w[(64 + k) * 64 + lane];
    float mn = wsum(acc) * 0.015625f;
    float d = acc - mn;
    float var = wsum(d * d) * 0.015625f;
    float x = d * rsqrtf(var + 1e-5f) * lng[lane] + lnb[lane];
    x = x >= 0.f ? x : 0.2f * x;
    float p = wsum(x * s2w[lane]);
    if (lane == 0) logits[wid] = p + s2b[0];
}

// =================== kP: final softmax over candidates ===================
// grid 4 x 512
__global__ __launch_bounds__(512) void kP(
    const float* __restrict__ logits, const int* __restrict__ nmask, float* __restrict__ out)
{
    __shared__ float red[512];
    __shared__ int anyf;
    int b = blockIdx.x; int t = threadIdx.x;
    bool cand = false;
    if (t < 511) cand = nmask[b * 512 + 1 + t] != 0;
    if (t == 0) anyf = 0;
    __syncthreads();
    if (cand) atomicOr(&anyf, 1);
    __syncthreads();
    if (t == 0 && anyf == 0) cand = true;
    float val = -3e38f;
    if (t < 511) val = cand ? logits[b * 511 + t] : -1e9f;
    red[t] = val; __syncthreads();
    for (int s = 256; s > 0; s >>= 1) { if (t < s) red[t] = fmaxf(red[t], red[t + s]); __syncthreads(); }
    float m = red[0]; __syncthreads();
    float p = (t < 511) ? __expf(val - m) : 0.f;
    red[t] = p; __syncthreads();
    for (int s = 256; s > 0; s >>= 1) { if (t < s) red[t] += red[t + s]; __syncthreads(); }
    float inv = 1.0f / red[0];
    if (t < 511) out[b * 511 + t] = p * inv;
}

extern "C" void kernel_launch(void* const* d_in, const int* in_sizes, int n_in,
                              void* d_out, int out_size, void* d_ws, size_t ws_size,
                              hipStream_t stream) {
    const float* nf    = (const float*)d_in[0];
    const float* ef    = (const float*)d_in[1];
    const int*   nm    = (const int*)d_in[2];
    const int*   em    = (const int*)d_in[3];
    const float* npw   = (const float*)d_in[4];
    const float* npb   = (const float*)d_in[5];
    const float* epw   = (const float*)d_in[6];
    const float* epb   = (const float*)d_in[7];
    const float* wq    = (const float*)d_in[8];
    const float* wk    = (const float*)d_in[9];
    const float* wv    = (const float*)d_in[10];
    const float* eb1w  = (const float*)d_in[11];
    const float* eb1b  = (const float*)d_in[12];
    const float* eblng = (const float*)d_in[13];
    const float* eblnb = (const float*)d_in[14];
    const float* eb2w  = (const float*)d_in[15];
    const float* eb2b  = (const float*)d_in[16];
    const float* s1wv  = (const float*)d_in[17];
    const float* s1bv  = (const float*)d_in[18];
    const float* s2wv  = (const float*)d_in[19];
    const float* s2bv  = (const float*)d_in[20];
    const float* wow   = (const float*)d_in[21];
    const float* wob   = (const float*)d_in[22];
    const float* ln1g  = (const float*)d_in[23];
    const float* ln1b  = (const float*)d_in[24];
    const float* ln2g  = (const float*)d_in[25];
    const float* ln2b  = (const float*)d_in[26];
    const float* f1w   = (const float*)d_in[27];
    const float* f1b   = (const float*)d_in[28];
    const float* f2w   = (const float*)d_in[29];
    const float* f2b   = (const float*)d_in[30];
    const float* sc1w  = (const float*)d_in[31];
    const float* sc1b  = (const float*)d_in[32];
    const float* sclng = (const float*)d_in[33];
    const float* sclnb = (const float*)d_in[34];
    const float* sc2w  = (const float*)d_in[35];
    const float* sc2b  = (const float*)d_in[36];

    char* W = (char*)d_ws;
    u64*   adj    = (u64*)(W + 0);              //   131,072 B
    unsigned char* spd = (unsigned char*)(W + 131072);   // 1,048,576 B
    u32*   elist  = (u32*)(W + 1179648);        //   786,432 B [2048][96]
    u32*   rowCnt = (u32*)(W + 1966080);        //     8,192 B
    float* vals   = (float*)(W + 1974272);      // 9,437,184 B [12][2048*96]
    float* hbuf   = (float*)(W + 11411456);     //   524,288 B
    float* Qb     = (float*)(W + 11935744);     //   524,288 B
    float* KT0    = (float*)(W + 12460032);     //   524,288 B
    float* VT0    = (float*)(W + 12984320);     //   524,288 B
    float* KT1    = (float*)(W + 13508608);     //   524,288 B
    float* VT1    = (float*)(W + 14032896);     //   524,288 B
    float* logits = (float*)(W + 14557184);     //     8,192 B
    float* egoAcc = (float*)(W + 14565376);     //     1,024 B
    float* attO   = (float*)(W + 14566400);     //   524,288 B

    float* out = (float*)d_out;                 // [probs 2044][h 131072]

    kA<<<512, 256, 0, stream>>>(em, nf, npw, npb, adj, elist, rowCnt, hbuf);
    kB<<<512, 256, 0, stream>>>(adj, ef, elist, rowCnt, hbuf, epw, epb,
                                eb1w, eb1b, eblng, eblnb, eb2w, eb2b,
                                wq, wk, wv, spd, vals, Qb, KT0, VT0);

    kAttn<<<2048, 256, 0, stream>>>(Qb, KT0, VT0, spd, elist, rowCnt, vals,
                                    s1wv, s1bv, s2wv, s2bv, nm, 0, attO);
    kLF<<<512, 256, 0, stream>>>(attO, wow, wob, ln1g, ln1b, f1w, f1b, f2w, f2b,
                                 ln2g, ln2b, wq + 4096, wk + 4096, wv + 4096,
                                 sc1w, sc1b, hbuf, Qb, KT1, VT1, egoAcc, 0, out);

    kAttn<<<2048, 256, 0, stream>>>(Qb, KT1, VT1, spd, elist, rowCnt, vals,
                                    s1wv, s1bv, s2wv, s2bv, nm, 1, attO);
    kLF<<<512, 256, 0, stream>>>(attO, wow, wob, ln1g, ln1b, f1w, f1b, f2w, f2b,
                                 ln2g, ln2b, wq + 8192, wk + 8192, wv + 8192,
                                 sc1w, sc1b, hbuf, Qb, KT0, VT0, egoAcc, 1, out);

    kAttn<<<2048, 256, 0, stream>>>(Qb, KT0, VT0, spd, elist, rowCnt, vals,
                                    s1wv, s1bv, s2wv, s2bv, nm, 2, attO);
    kLF<<<512, 256, 0, stream>>>(attO, wow, wob, ln1g, ln1b, f1w, f1b, f2w, f2b,
                                 ln2g, ln2b, wq, wk, wv,
                                 sc1w, sc1b, hbuf, Qb, KT1, VT1, egoAcc, 2, out);

    kS<<<511, 256, 0, stream>>>(hbuf, egoAcc, s1wv ? sc1w : sc1w, sclng, sclnb, sc2w, sc2b, logits);
    kP<<<4, 512, 0, stream>>>(logits, nm, out);
}